// Round 1
// baseline (1403.149 us; speedup 1.0000x reference)
//
#include <hip/hip_runtime.h>
#include <math.h>

#define NROWS 4096
#define INFEAT 512
#define HEADSZ 2002
#define SHORTLIST 2000
#define CUT1 10000
#define C0_CLS 8000
#define C1_CLS 40000

// ---------------------------------------------------------------------------
// GEMM: C[N,M] = act(A[N,K] @ W[M,K]^T + bias)    (row-major, W stored [M,K])
// 64x64 tile, BK=16, 256 threads, 4x4 register blocking.
// Requires K % 16 == 0 (true for all call sites: 512/2048/128).
// ---------------------------------------------------------------------------
template<bool BIAS, bool RELU>
__global__ __launch_bounds__(256) void gemm_nt(
    const float* __restrict__ A, const float* __restrict__ W,
    const float* __restrict__ bias, float* __restrict__ C,
    int N, int M, int K)
{
  __shared__ float As[16][65];   // [k][row], padded
  __shared__ float Ws[16][65];   // [k][col], padded
  const int tid = threadIdx.x;
  const int tx = tid & 15;       // col group
  const int ty = tid >> 4;       // row group
  const int row0 = blockIdx.y * 64;
  const int col0 = blockIdx.x * 64;

  const int lr = tid >> 2;       // 0..63 staging row
  const int kq = tid & 3;        // float4 slot

  float acc[4][4] = {};

  for (int k0 = 0; k0 < K; k0 += 16) {
    {
      const int gr = row0 + lr;
      float4 v = make_float4(0.f, 0.f, 0.f, 0.f);
      if (gr < N) v = *(const float4*)(A + (size_t)gr * K + k0 + kq * 4);
      As[kq*4+0][lr] = v.x; As[kq*4+1][lr] = v.y;
      As[kq*4+2][lr] = v.z; As[kq*4+3][lr] = v.w;

      const int gc = col0 + lr;
      float4 w = make_float4(0.f, 0.f, 0.f, 0.f);
      if (gc < M) w = *(const float4*)(W + (size_t)gc * K + k0 + kq * 4);
      Ws[kq*4+0][lr] = w.x; Ws[kq*4+1][lr] = w.y;
      Ws[kq*4+2][lr] = w.z; Ws[kq*4+3][lr] = w.w;
    }
    __syncthreads();
#pragma unroll
    for (int k = 0; k < 16; ++k) {
      float a[4], w[4];
#pragma unroll
      for (int i = 0; i < 4; ++i) a[i] = As[k][ty*4+i];
#pragma unroll
      for (int j = 0; j < 4; ++j) w[j] = Ws[k][tx*4+j];
#pragma unroll
      for (int i = 0; i < 4; ++i)
#pragma unroll
        for (int j = 0; j < 4; ++j)
          acc[i][j] = fmaf(a[i], w[j], acc[i][j]);
    }
    __syncthreads();
  }

#pragma unroll
  for (int i = 0; i < 4; ++i) {
    const int row = row0 + ty*4 + i;
    if (row >= N) continue;
#pragma unroll
    for (int j = 0; j < 4; ++j) {
      const int col = col0 + tx*4 + j;
      if (col >= M) continue;
      float v = acc[i][j];
      if (BIAS) v += bias[col];
      if (RELU) v = fmaxf(v, 0.f);
      C[(size_t)row * M + col] = v;
    }
  }
}

// ---------------------------------------------------------------------------
// Fused tail-cluster partial LSE:
//   logits[r, c] = dot(H[r, :K], Wt[c, :K]);  per-row online (max, sumexp)
//   over this block's class chunk; also gathers logit at clipped target.
// Block: 64 rows x (subChunks*64 classes). 256 threads = 16 class-groups x
// 16 row-groups; each thread owns 4 rows x 4 classes.
// ---------------------------------------------------------------------------
template<int K>
__global__ __launch_bounds__(256) void tail_lse(
    const float* __restrict__ H,    // [N, K]
    const float* __restrict__ Wt,   // [C, K]
    const int*   __restrict__ t,    // [N]
    int N, int C, int tbase,
    int subChunks, int nChunks,
    float* __restrict__ pm,         // [N, nChunks] partial max
    float* __restrict__ ps,         // [N, nChunks] partial sumexp
    float* __restrict__ tg)         // [N] gathered target logit
{
  __shared__ float Hs[64][K + 1];
  __shared__ float Ws[64][K + 1];
  __shared__ float red[64][16][2];

  const int tid = threadIdx.x;
  const int cx = tid & 15;        // class group 0..15
  const int ry = tid >> 4;        // row group 0..15
  const int r0 = blockIdx.x * 64;
  const int chunk = blockIdx.y;
  const int c0 = chunk * subChunks * 64;

  for (int i = tid; i < 64 * K; i += 256) {
    const int rr = i / K, kk = i % K;
    Hs[rr][kk] = H[(size_t)(r0 + rr) * K + kk];
  }

  int tl[4];
  float m[4], s[4];
#pragma unroll
  for (int j = 0; j < 4; ++j) {
    const int row = r0 + ry * 4 + j;
    const int tv = t[row] - tbase;
    tl[j] = min(max(tv, 0), C - 1);
    m[j] = -1e30f;
    s[j] = 0.f;
  }

  for (int sub = 0; sub < subChunks; ++sub) {
    const int cbase = c0 + sub * 64;
    __syncthreads();   // Ws (prev iter) no longer read; Hs ready (iter 0)
    for (int i = tid; i < 64 * K; i += 256) {
      const int cc = i / K, kk = i % K;
      const int cg = cbase + cc;
      Ws[cc][kk] = (cg < C) ? Wt[(size_t)cg * K + kk] : 0.f;
    }
    __syncthreads();

    float acc[4][4] = {};
#pragma unroll 8
    for (int k = 0; k < K; ++k) {
      float a[4], w[4];
#pragma unroll
      for (int j = 0; j < 4; ++j) a[j] = Hs[ry*4+j][k];
#pragma unroll
      for (int i = 0; i < 4; ++i) w[i] = Ws[cx*4+i][k];
#pragma unroll
      for (int j = 0; j < 4; ++j)
#pragma unroll
        for (int i = 0; i < 4; ++i)
          acc[j][i] = fmaf(a[j], w[i], acc[j][i]);
    }

#pragma unroll
    for (int j = 0; j < 4; ++j) {
      float mn = m[j];
#pragma unroll
      for (int i = 0; i < 4; ++i) {
        if (cbase + cx*4 + i < C) mn = fmaxf(mn, acc[j][i]);
      }
      if (mn > m[j]) { s[j] *= __expf(m[j] - mn); m[j] = mn; }
#pragma unroll
      for (int i = 0; i < 4; ++i) {
        const int cg = cbase + cx*4 + i;
        if (cg < C) {
          s[j] += __expf(acc[j][i] - mn);
          if (cg == tl[j]) tg[r0 + ry*4 + j] = acc[j][i];
        }
      }
    }
  }

#pragma unroll
  for (int j = 0; j < 4; ++j) {
    red[ry*4+j][cx][0] = m[j];
    red[ry*4+j][cx][1] = s[j];
  }
  __syncthreads();
  if (tid < 64) {
    float M = -1e30f;
    for (int c = 0; c < 16; ++c) M = fmaxf(M, red[tid][c][0]);
    float S = 0.f;
    for (int c = 0; c < 16; ++c) S += red[tid][c][1] * __expf(red[tid][c][0] - M);
    pm[(size_t)(r0 + tid) * nChunks + chunk] = M;
    ps[(size_t)(r0 + tid) * nChunks + chunk] = S;
  }
}

// ---------------------------------------------------------------------------
// Head LSE: one block per row over materialized head logits [N, 2002].
// Produces row LSE and the three gathered logits.
// ---------------------------------------------------------------------------
__global__ __launch_bounds__(256) void head_lse_kernel(
    const float* __restrict__ HL, const int* __restrict__ t,
    float* __restrict__ hlse, float* __restrict__ gsh,
    float* __restrict__ gc0, float* __restrict__ gc1)
{
  __shared__ float buf[HEADSZ];
  __shared__ float sred[256];
  const int row = blockIdx.x;
  const int tid = threadIdx.x;

  for (int i = tid; i < HEADSZ; i += 256) buf[i] = HL[(size_t)row * HEADSZ + i];
  __syncthreads();

  float v = -1e30f;
  for (int i = tid; i < HEADSZ; i += 256) v = fmaxf(v, buf[i]);
  sred[tid] = v;
  __syncthreads();
  for (int st = 128; st > 0; st >>= 1) {
    if (tid < st) sred[tid] = fmaxf(sred[tid], sred[tid + st]);
    __syncthreads();
  }
  const float mx = sred[0];
  __syncthreads();

  float sm = 0.f;
  for (int i = tid; i < HEADSZ; i += 256) sm += expf(buf[i] - mx);
  sred[tid] = sm;
  __syncthreads();
  for (int st = 128; st > 0; st >>= 1) {
    if (tid < st) sred[tid] += sred[tid + st];
    __syncthreads();
  }
  if (tid == 0) {
    hlse[row] = mx + logf(sred[0]);
    const int tv = t[row];
    gsh[row] = buf[min(tv, SHORTLIST - 1)];
    gc0[row] = buf[SHORTLIST];
    gc1[row] = buf[SHORTLIST + 1];
  }
}

// ---------------------------------------------------------------------------
// Combine partials into out[row]
// ---------------------------------------------------------------------------
__global__ __launch_bounds__(256) void combine_kernel(
    const int* __restrict__ t,
    const float* __restrict__ hlse, const float* __restrict__ gsh,
    const float* __restrict__ gc0, const float* __restrict__ gc1,
    const float* __restrict__ pm0, const float* __restrict__ ps0,
    const float* __restrict__ tg0, int nc0,
    const float* __restrict__ pm1, const float* __restrict__ ps1,
    const float* __restrict__ tg1, int nc1,
    float* __restrict__ out)
{
  const int row = blockIdx.x * blockDim.x + threadIdx.x;
  if (row >= NROWS) return;
  const int tv = t[row];
  const float hl = hlse[row];
  float o;
  if (tv < SHORTLIST) {
    o = gsh[row] - hl;
  } else if (tv < CUT1) {
    float M = -1e30f;
    for (int c = 0; c < nc0; ++c) M = fmaxf(M, pm0[row * nc0 + c]);
    float S = 0.f;
    for (int c = 0; c < nc0; ++c) S += ps0[row * nc0 + c] * expf(pm0[row * nc0 + c] - M);
    o = (gc0[row] - hl) + (tg0[row] - (M + logf(S)));
  } else {
    float M = -1e30f;
    for (int c = 0; c < nc1; ++c) M = fmaxf(M, pm1[row * nc1 + c]);
    float S = 0.f;
    for (int c = 0; c < nc1; ++c) S += ps1[row * nc1 + c] * expf(pm1[row * nc1 + c] - M);
    o = (gc1[row] - hl) + (tg1[row] - (M + logf(S)));
  }
  out[row] = o;
}

__global__ __launch_bounds__(256) void loss_kernel(
    const float* __restrict__ out, float* __restrict__ loss)
{
  __shared__ float sred[256];
  const int tid = threadIdx.x;
  float s = 0.f;
  for (int i = tid; i < NROWS; i += 256) s += out[i];
  sred[tid] = s;
  __syncthreads();
  for (int st = 128; st > 0; st >>= 1) {
    if (tid < st) sred[tid] += sred[tid + st];
    __syncthreads();
  }
  if (tid == 0) *loss = -sred[0] / (float)NROWS;
}

// ---------------------------------------------------------------------------
extern "C" void kernel_launch(void* const* d_in, const int* in_sizes, int n_in,
                              void* d_out, int out_size, void* d_ws, size_t ws_size,
                              hipStream_t stream)
{
  const float* x      = (const float*)d_in[0];
  const int*   t      = (const int*)  d_in[1];
  const float* W1     = (const float*)d_in[2];
  const float* b1     = (const float*)d_in[3];
  const float* W2     = (const float*)d_in[4];
  const float* b2     = (const float*)d_in[5];
  const float* W3     = (const float*)d_in[6];
  const float* b3     = (const float*)d_in[7];
  const float* head_W = (const float*)d_in[8];
  const float* head_b = (const float*)d_in[9];
  const float* t0a    = (const float*)d_in[10];
  const float* t0b    = (const float*)d_in[11];
  const float* t1a    = (const float*)d_in[12];
  const float* t1b    = (const float*)d_in[13];

  float* ws = (float*)d_ws;
  float* H1 = ws;               // [4096,2048]; dead after GEMM2
  float* HL = ws;               // [4096,2002] aliases H1 (8.2M <= 8.39M floats)
  size_t off = 4096ull * 2048;
  float* H2   = ws + off; off += 4096ull * 128;
  float* S    = ws + off; off += 4096ull * 512;
  float* h0   = ws + off; off += 4096ull * 128;
  float* h1   = ws + off; off += 4096ull * 32;
  float* hlse = ws + off; off += 4096;
  float* gsh  = ws + off; off += 4096;
  float* gc0  = ws + off; off += 4096;
  float* gc1  = ws + off; off += 4096;
  float* pm0  = ws + off; off += 4096ull * 5;
  float* ps0  = ws + off; off += 4096ull * 5;
  float* pm1  = ws + off; off += 4096ull * 25;
  float* ps1  = ws + off; off += 4096ull * 25;
  float* tg0  = ws + off; off += 4096;
  float* tg1  = ws + off; off += 4096;

  float* out = (float*)d_out;   // [4096] log-probs, then [1] loss

  const dim3 blk(256);

  // MLP: 512 -> 2048 -> 128 -> 512, ReLU each
  gemm_nt<true,  true ><<<dim3(2048/64, 4096/64), blk, 0, stream>>>(x,  W1, b1, H1, NROWS, 2048, 512);
  gemm_nt<true,  true ><<<dim3(128/64,  4096/64), blk, 0, stream>>>(H1, W2, b2, H2, NROWS, 128,  2048);
  gemm_nt<true,  true ><<<dim3(512/64,  4096/64), blk, 0, stream>>>(H2, W3, b3, S,  NROWS, 512,  128);

  // Head logits (bias, no relu) + tail projections (no bias)
  gemm_nt<true,  false><<<dim3((HEADSZ+63)/64, 4096/64), blk, 0, stream>>>(S, head_W, head_b, HL, NROWS, HEADSZ, 512);
  gemm_nt<false, false><<<dim3(128/64, 4096/64), blk, 0, stream>>>(S, t0a, nullptr, h0, NROWS, 128, 512);
  gemm_nt<false, false><<<dim3(1,      4096/64), blk, 0, stream>>>(S, t1a, nullptr, h1, NROWS, 32,  512);

  // Fused tail LSE partials: tail0 C=8000 K=128 (5 chunks x 1600 classes),
  // tail1 C=40000 K=32 (25 chunks x 1600 classes)
  tail_lse<128><<<dim3(4096/64, 5),  blk, 0, stream>>>(h0, t0b, t, NROWS, C0_CLS, SHORTLIST, 25, 5,  pm0, ps0, tg0);
  tail_lse<32> <<<dim3(4096/64, 25), blk, 0, stream>>>(h1, t1b, t, NROWS, C1_CLS, CUT1,      25, 25, pm1, ps1, tg1);

  // Head LSE + gathers
  head_lse_kernel<<<dim3(NROWS), blk, 0, stream>>>(HL, t, hlse, gsh, gc0, gc1);

  // Combine + loss
  combine_kernel<<<dim3((NROWS+255)/256), blk, 0, stream>>>(
      t, hlse, gsh, gc0, gc1, pm0, ps0, tg0, 5, pm1, ps1, tg1, 25, out);
  loss_kernel<<<dim3(1), blk, 0, stream>>>(out, out + NROWS);
}

// Round 2
// 478.872 us; speedup vs baseline: 2.9301x; 2.9301x over previous
//
#include <hip/hip_runtime.h>
#include <math.h>

typedef __attribute__((ext_vector_type(8))) short bf16x8;
typedef __attribute__((ext_vector_type(4))) float f32x4;

#define NROWS 4096
#define SHORTLIST 2000
#define HEADC 2002
#define CUT1 10000
#define C0_CLS 8000
#define C1_CLS 40000

__device__ __forceinline__ unsigned short f2b(float f) {
  unsigned u = __float_as_uint(f);
  unsigned r = (u + 0x7FFFu + ((u >> 16) & 1u)) >> 16;
  return (unsigned short)r;
}

// ---------------------------------------------------------------------------
// f32 -> bf16 (RNE), vectorized x4
// ---------------------------------------------------------------------------
__global__ __launch_bounds__(256) void cvt_bf16(const float* __restrict__ in,
                                                unsigned short* __restrict__ out,
                                                int n4) {
  int i = blockIdx.x * 256 + threadIdx.x;
  if (i >= n4) return;
  float4 v = ((const float4*)in)[i];
  ushort4 o;
  o.x = f2b(v.x); o.y = f2b(v.y); o.z = f2b(v.z); o.w = f2b(v.w);
  ((ushort4*)out)[i] = o;
}

// ---------------------------------------------------------------------------
// LDS-free MFMA GEMM: C_bf16[M,N] = act(A_bf16[M,K] @ W_bf16[N,K]^T + bias)
// Wave computes a 32x32 tile (4 MFMAs + 4x16B loads per 32-k block).
// Block = 4 waves arranged WR x WC (tile WR*32 x WC*32). K % 32 == 0.
// Fragment layout (16x16x32): A/B lane l holds 8 contiguous bf16 at
// row/col (l&15), k-octet (l>>4). D: col = l&15, row = 4*(l>>4)+j.
// ---------------------------------------------------------------------------
template<int WR, int WC, bool BIAS, bool RELU>
__global__ __launch_bounds__(256) void gemm_mfma(
    const unsigned short* __restrict__ A, const unsigned short* __restrict__ W,
    const float* __restrict__ bias, unsigned short* __restrict__ C,
    int M, int N, int K)
{
  const int lane = threadIdx.x & 63;
  const int wv   = threadIdx.x >> 6;
  const int cl   = lane & 15;
  const int ko   = lane >> 4;
  const int rw   = (blockIdx.y * WR + (wv / WC)) * 32;
  const int cw   = (blockIdx.x * WC + (wv % WC)) * 32;

  f32x4 acc[2][2];
#pragma unroll
  for (int p = 0; p < 2; ++p)
#pragma unroll
    for (int q = 0; q < 2; ++q) acc[p][q] = (f32x4){0.f, 0.f, 0.f, 0.f};

  const unsigned short* ap0 = A + (size_t)(rw + cl) * K + ko * 8;
  const unsigned short* ap1 = ap0 + (size_t)16 * K;
  const unsigned short* bp0 = W + (size_t)(cw + cl) * K + ko * 8;
  const unsigned short* bp1 = bp0 + (size_t)16 * K;

  for (int kb = 0; kb < K; kb += 32) {
    bf16x8 a0 = *(const bf16x8*)(ap0 + kb);
    bf16x8 a1 = *(const bf16x8*)(ap1 + kb);
    bf16x8 b0 = *(const bf16x8*)(bp0 + kb);
    bf16x8 b1 = *(const bf16x8*)(bp1 + kb);
    acc[0][0] = __builtin_amdgcn_mfma_f32_16x16x32_bf16(a0, b0, acc[0][0], 0, 0, 0);
    acc[0][1] = __builtin_amdgcn_mfma_f32_16x16x32_bf16(a0, b1, acc[0][1], 0, 0, 0);
    acc[1][0] = __builtin_amdgcn_mfma_f32_16x16x32_bf16(a1, b0, acc[1][0], 0, 0, 0);
    acc[1][1] = __builtin_amdgcn_mfma_f32_16x16x32_bf16(a1, b1, acc[1][1], 0, 0, 0);
  }

#pragma unroll
  for (int q = 0; q < 2; ++q) {
    const int col = cw + q * 16 + cl;
    float bs = 0.f;
    if (BIAS) bs = bias[col];
#pragma unroll
    for (int p = 0; p < 2; ++p) {
#pragma unroll
      for (int j = 0; j < 4; ++j) {
        const int R = rw + p * 16 + 4 * ko + j;
        float v = acc[p][q][j] + bs;
        if (RELU) v = fmaxf(v, 0.f);
        C[(size_t)R * N + col] = f2b(v);
      }
    }
  }
}

// ---------------------------------------------------------------------------
// Fused MFMA GEMV + online log-sum-exp (no LDS).
// Per wave: 16 rows; loop over 16-class chunks of this block's y-slice.
// Per chunk: KBLK MFMAs give full-K logits; online (m,s) per lane over its
// class column; shuffle-reduce over the 16 class-lanes at the end.
// HEAD: +bias, mask c>=C to -inf, gather clip-target + cols C-2, C-1.
// TAIL: gather clip(t - tbase).
// ---------------------------------------------------------------------------
template<int KBLK, bool HEAD>
__global__ __launch_bounds__(256) void fused_lse(
    const unsigned short* __restrict__ H,   // [NROWS][K] bf16
    const unsigned short* __restrict__ W,   // [C][K] bf16
    const float* __restrict__ bias,         // head only (f32)
    const int*   __restrict__ t,
    int C, int tbase, int CPB, int NCB,
    float* __restrict__ pm, float* __restrict__ ps,
    float* __restrict__ tg, float* __restrict__ g0, float* __restrict__ g1)
{
  const int K    = KBLK * 32;
  const int lane = threadIdx.x & 63;
  const int wv   = threadIdx.x >> 6;
  const int cl   = lane & 15;
  const int ko   = lane >> 4;
  const int r0   = blockIdx.x * 64 + wv * 16;

  bf16x8 aF[KBLK];
  const unsigned short* ap = H + (size_t)(r0 + cl) * K + ko * 8;
#pragma unroll
  for (int kk = 0; kk < KBLK; ++kk) aF[kk] = *(const bf16x8*)(ap + kk * 32);

  int   tcl[4];
  float m[4], s[4];
#pragma unroll
  for (int j = 0; j < 4; ++j) {
    const int R  = r0 + 4 * ko + j;
    const int tv = t[R] - tbase;
    const int hi = HEAD ? (SHORTLIST - 1) : (C - 1);
    tcl[j] = min(max(tv, 0), hi);
    m[j] = -1e30f;
    s[j] = 0.f;
  }

  for (int ch = 0; ch < CPB; ++ch) {
    const int cb = (blockIdx.y * CPB + ch) * 16;
    const int c  = cb + cl;
    const int crow = HEAD ? min(c, C - 1) : c;   // clamp OOB pad reads
    const unsigned short* wp = W + (size_t)crow * K + ko * 8;

    f32x4 acc = (f32x4){0.f, 0.f, 0.f, 0.f};
#pragma unroll
    for (int kk = 0; kk < KBLK; ++kk)
      acc = __builtin_amdgcn_mfma_f32_16x16x32_bf16(aF[kk], *(const bf16x8*)(wp + kk * 32), acc, 0, 0, 0);

    float bc = 0.f;
    if (HEAD) bc = bias[crow];

#pragma unroll
    for (int j = 0; j < 4; ++j) {
      float v = acc[j] + bc;
      if (HEAD && c >= C) v = -3e38f;
      const int R = r0 + 4 * ko + j;
      if (c == tcl[j]) tg[R] = v;
      if (HEAD) {
        if (c == C - 2) g0[R] = v;
        if (c == C - 1) g1[R] = v;
      }
      float mn = fmaxf(m[j], v);
      s[j] = s[j] * __expf(m[j] - mn) + __expf(v - mn);
      m[j] = mn;
    }
  }

  // reduce (m,s) across the 16 class-lanes (xor within 16 keeps row group)
#pragma unroll
  for (int mask = 1; mask <= 8; mask <<= 1) {
#pragma unroll
    for (int j = 0; j < 4; ++j) {
      float mo = __shfl_xor(m[j], mask);
      float so = __shfl_xor(s[j], mask);
      float mn = fmaxf(m[j], mo);
      s[j] = s[j] * __expf(m[j] - mn) + so * __expf(mo - mn);
      m[j] = mn;
    }
  }
  if (cl == 0) {
#pragma unroll
    for (int j = 0; j < 4; ++j) {
      const int R = r0 + 4 * ko + j;
      pm[(size_t)R * NCB + blockIdx.y] = m[j];
      ps[(size_t)R * NCB + blockIdx.y] = s[j];
    }
  }
}

// ---------------------------------------------------------------------------
// Combine partials into out[row]
// ---------------------------------------------------------------------------
__global__ __launch_bounds__(256) void combine_kernel(
    const int* __restrict__ t,
    const float* __restrict__ pmh, const float* __restrict__ psh,
    const float* __restrict__ gsh, const float* __restrict__ gc0,
    const float* __restrict__ gc1,
    const float* __restrict__ pm0, const float* __restrict__ ps0,
    const float* __restrict__ tg0,
    const float* __restrict__ pm1, const float* __restrict__ ps1,
    const float* __restrict__ tg1,
    float* __restrict__ out)
{
  const int r = blockIdx.x * 256 + threadIdx.x;
  if (r >= NROWS) return;

  float M = -1e30f, S = 0.f;
  for (int c = 0; c < 9; ++c) M = fmaxf(M, pmh[r * 9 + c]);
  for (int c = 0; c < 9; ++c) S += psh[r * 9 + c] * expf(pmh[r * 9 + c] - M);
  const float hl = M + logf(S);

  const int tv = t[r];
  float o;
  if (tv < SHORTLIST) {
    o = gsh[r] - hl;
  } else if (tv < CUT1) {
    float M0 = -1e30f, S0 = 0.f;
    for (int c = 0; c < 10; ++c) M0 = fmaxf(M0, pm0[r * 10 + c]);
    for (int c = 0; c < 10; ++c) S0 += ps0[r * 10 + c] * expf(pm0[r * 10 + c] - M0);
    o = (gc0[r] - hl) + (tg0[r] - (M0 + logf(S0)));
  } else {
    float M1 = -1e30f, S1 = 0.f;
    for (int c = 0; c < 25; ++c) M1 = fmaxf(M1, pm1[r * 25 + c]);
    for (int c = 0; c < 25; ++c) S1 += ps1[r * 25 + c] * expf(pm1[r * 25 + c] - M1);
    o = (gc1[r] - hl) + (tg1[r] - (M1 + logf(S1)));
  }
  out[r] = o;
}

__global__ __launch_bounds__(256) void loss_kernel(
    const float* __restrict__ out, float* __restrict__ loss)
{
  __shared__ float sred[256];
  const int tid = threadIdx.x;
  float s = 0.f;
  for (int i = tid; i < NROWS; i += 256) s += out[i];
  sred[tid] = s;
  __syncthreads();
  for (int st = 128; st > 0; st >>= 1) {
    if (tid < st) sred[tid] += sred[tid + st];
    __syncthreads();
  }
  if (tid == 0) *loss = -sred[0] / (float)NROWS;
}

// ---------------------------------------------------------------------------
extern "C" void kernel_launch(void* const* d_in, const int* in_sizes, int n_in,
                              void* d_out, int out_size, void* d_ws, size_t ws_size,
                              hipStream_t stream)
{
  const float* x      = (const float*)d_in[0];
  const int*   t      = (const int*)  d_in[1];
  const float* W1     = (const float*)d_in[2];
  const float* b1     = (const float*)d_in[3];
  const float* W2     = (const float*)d_in[4];
  const float* b2     = (const float*)d_in[5];
  const float* W3     = (const float*)d_in[6];
  const float* b3     = (const float*)d_in[7];
  const float* head_W = (const float*)d_in[8];
  const float* head_b = (const float*)d_in[9];
  const float* t0a    = (const float*)d_in[10];
  const float* t0b    = (const float*)d_in[11];
  const float* t1a    = (const float*)d_in[12];
  const float* t1b    = (const float*)d_in[13];

  // ---- workspace layout (bf16 region, then f32 region) ----
  unsigned short* p16 = (unsigned short*)d_ws;
  unsigned short* xb  = p16; p16 += 4096ull * 512;
  unsigned short* W1b = p16; p16 += 2048ull * 512;
  unsigned short* W2b = p16; p16 += 128ull  * 2048;
  unsigned short* W3b = p16; p16 += 512ull  * 128;
  unsigned short* hWb = p16; p16 += (size_t)HEADC * 512;
  unsigned short* t0ab= p16; p16 += 128ull  * 512;
  unsigned short* t0bb= p16; p16 += 8000ull * 128;
  unsigned short* t1ab= p16; p16 += 32ull   * 512;
  unsigned short* t1bb= p16; p16 += 40000ull* 32;
  unsigned short* H1b = p16; p16 += 4096ull * 2048;
  unsigned short* H2b = p16; p16 += 4096ull * 128;
  unsigned short* Sb  = p16; p16 += 4096ull * 512;
  unsigned short* h0b = p16; p16 += 4096ull * 128;
  unsigned short* h1b = p16; p16 += 4096ull * 32;

  float* pf  = (float*)p16;
  float* pmh = pf; pf += 4096 * 9;
  float* psh = pf; pf += 4096 * 9;
  float* pm0 = pf; pf += 4096 * 10;
  float* ps0 = pf; pf += 4096 * 10;
  float* pm1 = pf; pf += 4096 * 25;
  float* ps1 = pf; pf += 4096 * 25;
  float* gsh = pf; pf += 4096;
  float* gc0 = pf; pf += 4096;
  float* gc1 = pf; pf += 4096;
  float* tg0 = pf; pf += 4096;
  float* tg1 = pf; pf += 4096;

  float* out = (float*)d_out;   // [4096] log-probs, then [1] loss

  auto cvt = [&](const float* src, unsigned short* dst, size_t n) {
    int n4 = (int)(n / 4);
    cvt_bf16<<<dim3((n4 + 255) / 256), dim3(256), 0, stream>>>(src, dst, n4);
  };

  // ---- convert inputs/weights to bf16 ----
  cvt(x,      xb,   4096ull * 512);
  cvt(W1,     W1b,  2048ull * 512);
  cvt(W2,     W2b,  128ull  * 2048);
  cvt(W3,     W3b,  512ull  * 128);
  cvt(head_W, hWb,  (size_t)HEADC * 512);
  cvt(t0a,    t0ab, 128ull  * 512);
  cvt(t0b,    t0bb, 8000ull * 128);
  cvt(t1a,    t1ab, 32ull   * 512);
  cvt(t1b,    t1bb, 40000ull* 32);

  const dim3 blk(256);

  // ---- MLP (bf16 MFMA): 512 -> 2048 -> 128 -> 512, ReLU each ----
  gemm_mfma<2, 2, true,  true ><<<dim3(2048/64, 4096/64), blk, 0, stream>>>(xb,  W1b, b1, H1b, 4096, 2048, 512);
  gemm_mfma<2, 2, true,  true ><<<dim3(128/64,  4096/64), blk, 0, stream>>>(H1b, W2b, b2, H2b, 4096, 128,  2048);
  gemm_mfma<2, 2, true,  true ><<<dim3(512/64,  4096/64), blk, 0, stream>>>(H2b, W3b, b3, Sb,  4096, 512,  128);

  // ---- tail low-rank projections ----
  gemm_mfma<2, 2, false, false><<<dim3(128/64,  4096/64), blk, 0, stream>>>(Sb, t0ab, nullptr, h0b, 4096, 128, 512);
  gemm_mfma<4, 1, false, false><<<dim3(1,       4096/128),blk, 0, stream>>>(Sb, t1ab, nullptr, h1b, 4096, 32,  512);

  // ---- fused MFMA + online LSE ----
  // head: 126 chunks = 9 blocks x 14;  tail0: 500 = 10 x 50;  tail1: 2500 = 25 x 100
  fused_lse<16, true ><<<dim3(64, 9),  blk, 0, stream>>>(Sb,  hWb,  head_b, t, HEADC,  0,        14,  9,  pmh, psh, gsh, gc0, gc1);
  fused_lse<4,  false><<<dim3(64, 10), blk, 0, stream>>>(h0b, t0bb, nullptr, t, C0_CLS, SHORTLIST, 50, 10, pm0, ps0, tg0, nullptr, nullptr);
  fused_lse<1,  false><<<dim3(64, 25), blk, 0, stream>>>(h1b, t1bb, nullptr, t, C1_CLS, CUT1,     100, 25, pm1, ps1, tg1, nullptr, nullptr);

  // ---- combine + loss ----
  combine_kernel<<<dim3((NROWS + 255) / 256), blk, 0, stream>>>(
      t, pmh, psh, gsh, gc0, gc1, pm0, ps0, tg0, pm1, ps1, tg1, out);
  loss_kernel<<<dim3(1), blk, 0, stream>>>(out, out + NROWS);
}

// Round 3
// 441.155 us; speedup vs baseline: 3.1806x; 1.0855x over previous
//
#include <hip/hip_runtime.h>
#include <math.h>

typedef __attribute__((ext_vector_type(8))) short bf16x8;
typedef __attribute__((ext_vector_type(4))) float f32x4;

#define NROWS 4096
#define SHORTLIST 2000
#define HEADC 2002
#define CUT1 10000
#define C0_CLS 8000
#define C1_CLS 40000
#define L2E 1.4426950408889634f
#define LN2 0.6931471805599453f

__device__ __forceinline__ float fexp2(float x) {
#if __has_builtin(__builtin_amdgcn_exp2f)
  return __builtin_amdgcn_exp2f(x);
#else
  return exp2f(x);
#endif
}

__device__ __forceinline__ unsigned short f2b(float f) {
  unsigned u = __float_as_uint(f);
  unsigned r = (u + 0x7FFFu + ((u >> 16) & 1u)) >> 16;
  return (unsigned short)r;
}
__device__ __forceinline__ float b2f(unsigned short u) {
  return __uint_as_float(((unsigned)u) << 16);
}

// ---------------------------------------------------------------------------
// f32 -> bf16 (RNE), vectorized x4
// ---------------------------------------------------------------------------
__global__ __launch_bounds__(256) void cvt_bf16(const float* __restrict__ in,
                                                unsigned short* __restrict__ out,
                                                int n4) {
  int i = blockIdx.x * 256 + threadIdx.x;
  if (i >= n4) return;
  float4 v = ((const float4*)in)[i];
  ushort4 o;
  o.x = f2b(v.x); o.y = f2b(v.y); o.z = f2b(v.z); o.w = f2b(v.w);
  ((ushort4*)out)[i] = o;
}

// ---------------------------------------------------------------------------
// LDS-free MFMA GEMM: C_bf16[M,N] = act(A[M,K] @ W[N,K]^T + bias)
// Per-wave tile 64x32 (8 MFMAs per 6x16B loads). Block = WR x WC waves
// (WR*WC == 4): block tile (WR*64) x (WC*32). K % 32 == 0.
// ---------------------------------------------------------------------------
template<int WR, int WC, bool BIAS, bool RELU>
__global__ __launch_bounds__(256) void gemm_mfma(
    const unsigned short* __restrict__ A, const unsigned short* __restrict__ W,
    const float* __restrict__ bias, unsigned short* __restrict__ C,
    int M, int N, int K)
{
  const int lane = threadIdx.x & 63;
  const int wv   = threadIdx.x >> 6;
  const int cl   = lane & 15;
  const int ko   = lane >> 4;
  const int rw   = (blockIdx.y * WR + (wv / WC)) * 64;
  const int cw   = (blockIdx.x * WC + (wv % WC)) * 32;

  f32x4 acc[4][2];
#pragma unroll
  for (int p = 0; p < 4; ++p)
#pragma unroll
    for (int q = 0; q < 2; ++q) acc[p][q] = (f32x4){0.f, 0.f, 0.f, 0.f};

  const unsigned short* ap = A + (size_t)(rw + cl) * K + ko * 8;
  const unsigned short* bp = W + (size_t)(cw + cl) * K + ko * 8;
  const size_t rstep = (size_t)16 * K;

  for (int kb = 0; kb < K; kb += 32) {
    bf16x8 a[4], b[2];
#pragma unroll
    for (int p = 0; p < 4; ++p) a[p] = *(const bf16x8*)(ap + p * rstep + kb);
#pragma unroll
    for (int q = 0; q < 2; ++q) b[q] = *(const bf16x8*)(bp + q * rstep + kb);
#pragma unroll
    for (int p = 0; p < 4; ++p)
#pragma unroll
      for (int q = 0; q < 2; ++q)
        acc[p][q] = __builtin_amdgcn_mfma_f32_16x16x32_bf16(a[p], b[q], acc[p][q], 0, 0, 0);
  }

#pragma unroll
  for (int q = 0; q < 2; ++q) {
    const int col = cw + q * 16 + cl;
    float bs = 0.f;
    if (BIAS) bs = bias[col];
#pragma unroll
    for (int p = 0; p < 4; ++p) {
#pragma unroll
      for (int j = 0; j < 4; ++j) {
        const int R = rw + p * 16 + 4 * ko + j;
        float v = acc[p][q][j] + bs;
        if (RELU) v = fmaxf(v, 0.f);
        C[(size_t)R * N + col] = f2b(v);
      }
    }
  }
}

// ---------------------------------------------------------------------------
// Fused MFMA GEMV + deferred-max online LSE in exp2 domain (no LDS, no gather).
// Per wave: 16 rows; loop over 16-class chunks of this block's y-slice.
// pm/ps partials per (row, blockIdx.y): m in log2 units, s = sum 2^(v-m).
// ---------------------------------------------------------------------------
template<int KBLK, bool HEAD>
__global__ __launch_bounds__(256) void fused_lse(
    const unsigned short* __restrict__ H,   // [NROWS][K] bf16
    const unsigned short* __restrict__ W,   // [C][K] bf16
    const float* __restrict__ bias,         // head only (f32)
    int C, int CPB, int NCB,
    float* __restrict__ pm, float* __restrict__ ps)
{
  const int K    = KBLK * 32;
  const int lane = threadIdx.x & 63;
  const int wv   = threadIdx.x >> 6;
  const int cl   = lane & 15;
  const int ko   = lane >> 4;
  const int r0   = blockIdx.x * 64 + wv * 16;

  bf16x8 aF[KBLK];
  const unsigned short* ap = H + (size_t)(r0 + cl) * K + ko * 8;
#pragma unroll
  for (int kk = 0; kk < KBLK; ++kk) aF[kk] = *(const bf16x8*)(ap + kk * 32);

  float m[4], s[4];
#pragma unroll
  for (int j = 0; j < 4; ++j) { m[j] = -1e30f; s[j] = 0.f; }

  const int cb0 = blockIdx.y * CPB * 16;
  const unsigned short* wp = W + (size_t)(cb0 + cl) * K + ko * 8;
  const size_t wstep = (size_t)16 * K;

  for (int ch = 0; ch < CPB; ++ch) {
    const unsigned short* wpc;
    int c = 0;
    if (HEAD) {
      c = cb0 + ch * 16 + cl;
      wpc = W + (size_t)min(c, C - 1) * K + ko * 8;
    } else {
      wpc = wp;
    }

    f32x4 acc = (f32x4){0.f, 0.f, 0.f, 0.f};
#pragma unroll
    for (int kk = 0; kk < KBLK; ++kk)
      acc = __builtin_amdgcn_mfma_f32_16x16x32_bf16(aF[kk], *(const bf16x8*)(wpc + kk * 32), acc, 0, 0, 0);

    float bl2 = 0.f;
    if (HEAD) bl2 = bias[min(c, C - 1)] * L2E;

    float v[4];
#pragma unroll
    for (int j = 0; j < 4; ++j) {
      v[j] = fmaf(acc[j], L2E, bl2);
      if (HEAD && c >= C) v[j] = -1e30f;
    }
    const float d01 = fmaxf(v[0] - m[0], v[1] - m[1]);
    const float d23 = fmaxf(v[2] - m[2], v[3] - m[3]);
    if (__any(fmaxf(d01, d23) > 8.f)) {
#pragma unroll
      for (int j = 0; j < 4; ++j) {
        const float mn = fmaxf(m[j], v[j]);
        s[j] *= fexp2(m[j] - mn);
        m[j] = mn;
      }
    }
#pragma unroll
    for (int j = 0; j < 4; ++j)
      s[j] += fexp2(v[j] - m[j]);

    if (!HEAD) wp += wstep;
  }

  // reduce (m,s) across the 16 class-lanes
#pragma unroll
  for (int mask = 1; mask <= 8; mask <<= 1) {
#pragma unroll
    for (int j = 0; j < 4; ++j) {
      const float mo = __shfl_xor(m[j], mask);
      const float so = __shfl_xor(s[j], mask);
      const float mn = fmaxf(m[j], mo);
      s[j] = s[j] * fexp2(m[j] - mn) + so * fexp2(mo - mn);
      m[j] = mn;
    }
  }
  if (cl == 0) {
#pragma unroll
    for (int j = 0; j < 4; ++j) {
      const int R = r0 + 4 * ko + j;
      pm[(size_t)R * NCB + blockIdx.y] = m[j];
      ps[(size_t)R * NCB + blockIdx.y] = s[j];
    }
  }
}

// ---------------------------------------------------------------------------
// Target / cluster-logit gather: per row compute the 5 needed raw logits
// as explicit dot products. One 64-lane wave per row (4 rows / block).
// ---------------------------------------------------------------------------
__global__ __launch_bounds__(256) void gather_kernel(
    const unsigned short* __restrict__ Sb,   // [4096][512]
    const unsigned short* __restrict__ hWb,  // [2002][512]
    const float* __restrict__ head_b,
    const unsigned short* __restrict__ h0b,  // [4096][128]
    const unsigned short* __restrict__ t0bb, // [8000][128]
    const unsigned short* __restrict__ h1b,  // [4096][32]
    const unsigned short* __restrict__ t1bb, // [40000][32]
    const int* __restrict__ t,
    float* __restrict__ gsh, float* __restrict__ gc0, float* __restrict__ gc1,
    float* __restrict__ tg0, float* __restrict__ tg1)
{
  const int lane = threadIdx.x & 63;
  const int row  = blockIdx.x * 4 + (threadIdx.x >> 6);
  const int tv   = t[row];
  const int ch   = min(max(tv, 0), SHORTLIST - 1);
  const int c0   = min(max(tv - SHORTLIST, 0), C0_CLS - 1);
  const int c1   = min(max(tv - CUT1, 0), C1_CLS - 1);

  float acc[5] = {0.f, 0.f, 0.f, 0.f, 0.f};

  {
    bf16x8 sv = *(const bf16x8*)(Sb + (size_t)row * 512 + lane * 8);
    bf16x8 w0 = *(const bf16x8*)(hWb + (size_t)ch * 512 + lane * 8);
    bf16x8 w1 = *(const bf16x8*)(hWb + (size_t)SHORTLIST * 512 + lane * 8);
    bf16x8 w2 = *(const bf16x8*)(hWb + (size_t)(SHORTLIST + 1) * 512 + lane * 8);
#pragma unroll
    for (int e = 0; e < 8; ++e) {
      const float sf = b2f((unsigned short)sv[e]);
      acc[0] = fmaf(sf, b2f((unsigned short)w0[e]), acc[0]);
      acc[1] = fmaf(sf, b2f((unsigned short)w1[e]), acc[1]);
      acc[2] = fmaf(sf, b2f((unsigned short)w2[e]), acc[2]);
    }
  }
  if (lane < 16) {
    bf16x8 hv = *(const bf16x8*)(h0b + (size_t)row * 128 + lane * 8);
    bf16x8 wv = *(const bf16x8*)(t0bb + (size_t)c0 * 128 + lane * 8);
#pragma unroll
    for (int e = 0; e < 8; ++e)
      acc[3] = fmaf(b2f((unsigned short)hv[e]), b2f((unsigned short)wv[e]), acc[3]);
  }
  if (lane < 4) {
    bf16x8 hv = *(const bf16x8*)(h1b + (size_t)row * 32 + lane * 8);
    bf16x8 wv = *(const bf16x8*)(t1bb + (size_t)c1 * 32 + lane * 8);
#pragma unroll
    for (int e = 0; e < 8; ++e)
      acc[4] = fmaf(b2f((unsigned short)hv[e]), b2f((unsigned short)wv[e]), acc[4]);
  }

#pragma unroll
  for (int mask = 1; mask < 64; mask <<= 1)
#pragma unroll
    for (int k = 0; k < 5; ++k) acc[k] += __shfl_xor(acc[k], mask);

  if (lane == 0) {
    gsh[row] = acc[0] + head_b[ch];
    gc0[row] = acc[1] + head_b[SHORTLIST];
    gc1[row] = acc[2] + head_b[SHORTLIST + 1];
    tg0[row] = acc[3];
    tg1[row] = acc[4];
  }
}

// ---------------------------------------------------------------------------
// Combine partials (log2 domain) into out[row]
// ---------------------------------------------------------------------------
__global__ __launch_bounds__(256) void combine_kernel(
    const int* __restrict__ t,
    const float* __restrict__ pmh, const float* __restrict__ psh,
    const float* __restrict__ gsh, const float* __restrict__ gc0,
    const float* __restrict__ gc1,
    const float* __restrict__ pm0, const float* __restrict__ ps0,
    const float* __restrict__ tg0,
    const float* __restrict__ pm1, const float* __restrict__ ps1,
    const float* __restrict__ tg1,
    float* __restrict__ out)
{
  const int r = blockIdx.x * 256 + threadIdx.x;
  if (r >= NROWS) return;

  float M = -1e30f, S = 0.f;
  for (int c = 0; c < 9; ++c) M = fmaxf(M, pmh[r * 9 + c]);
  for (int c = 0; c < 9; ++c) S += psh[r * 9 + c] * fexp2(pmh[r * 9 + c] - M);
  const float hl = (M + log2f(S)) * LN2;

  const int tv = t[r];
  float o;
  if (tv < SHORTLIST) {
    o = gsh[r] - hl;
  } else if (tv < CUT1) {
    float M0 = -1e30f, S0 = 0.f;
    for (int c = 0; c < 10; ++c) M0 = fmaxf(M0, pm0[r * 10 + c]);
    for (int c = 0; c < 10; ++c) S0 += ps0[r * 10 + c] * fexp2(pm0[r * 10 + c] - M0);
    o = (gc0[r] - hl) + (tg0[r] - (M0 + log2f(S0)) * LN2);
  } else {
    float M1 = -1e30f, S1 = 0.f;
    for (int c = 0; c < 25; ++c) M1 = fmaxf(M1, pm1[r * 25 + c]);
    for (int c = 0; c < 25; ++c) S1 += ps1[r * 25 + c] * fexp2(pm1[r * 25 + c] - M1);
    o = (gc1[r] - hl) + (tg1[r] - (M1 + log2f(S1)) * LN2);
  }
  out[r] = o;
}

__global__ __launch_bounds__(256) void loss_kernel(
    const float* __restrict__ out, float* __restrict__ loss)
{
  __shared__ float sred[256];
  const int tid = threadIdx.x;
  float s = 0.f;
  for (int i = tid; i < NROWS; i += 256) s += out[i];
  sred[tid] = s;
  __syncthreads();
  for (int st = 128; st > 0; st >>= 1) {
    if (tid < st) sred[tid] += sred[tid + st];
    __syncthreads();
  }
  if (tid == 0) *loss = -sred[0] / (float)NROWS;
}

// ---------------------------------------------------------------------------
extern "C" void kernel_launch(void* const* d_in, const int* in_sizes, int n_in,
                              void* d_out, int out_size, void* d_ws, size_t ws_size,
                              hipStream_t stream)
{
  const float* x      = (const float*)d_in[0];
  const int*   t      = (const int*)  d_in[1];
  const float* W1     = (const float*)d_in[2];
  const float* b1     = (const float*)d_in[3];
  const float* W2     = (const float*)d_in[4];
  const float* b2     = (const float*)d_in[5];
  const float* W3     = (const float*)d_in[6];
  const float* b3     = (const float*)d_in[7];
  const float* head_W = (const float*)d_in[8];
  const float* head_b = (const float*)d_in[9];
  const float* t0a    = (const float*)d_in[10];
  const float* t0b    = (const float*)d_in[11];
  const float* t1a    = (const float*)d_in[12];
  const float* t1b    = (const float*)d_in[13];

  // ---- workspace layout (bf16 region, then f32 region) ----
  unsigned short* p16 = (unsigned short*)d_ws;
  unsigned short* xb  = p16; p16 += 4096ull * 512;
  unsigned short* W1b = p16; p16 += 2048ull * 512;
  unsigned short* W2b = p16; p16 += 128ull  * 2048;
  unsigned short* W3b = p16; p16 += 512ull  * 128;
  unsigned short* hWb = p16; p16 += (size_t)HEADC * 512;
  unsigned short* t0ab= p16; p16 += 128ull  * 512;
  unsigned short* t0bb= p16; p16 += 8000ull * 128;
  unsigned short* t1ab= p16; p16 += 32ull   * 512;
  unsigned short* t1bb= p16; p16 += 40000ull* 32;
  unsigned short* H1b = p16; p16 += 4096ull * 2048;
  unsigned short* H2b = p16; p16 += 4096ull * 128;
  unsigned short* Sb  = p16; p16 += 4096ull * 512;
  unsigned short* h0b = p16; p16 += 4096ull * 128;
  unsigned short* h1b = p16; p16 += 4096ull * 32;

  float* pf  = (float*)p16;
  float* pmh = pf; pf += 4096 * 9;
  float* psh = pf; pf += 4096 * 9;
  float* pm0 = pf; pf += 4096 * 10;
  float* ps0 = pf; pf += 4096 * 10;
  float* pm1 = pf; pf += 4096 * 25;
  float* ps1 = pf; pf += 4096 * 25;
  float* gsh = pf; pf += 4096;
  float* gc0 = pf; pf += 4096;
  float* gc1 = pf; pf += 4096;
  float* tg0 = pf; pf += 4096;
  float* tg1 = pf; pf += 4096;

  float* out = (float*)d_out;   // [4096] log-probs, then [1] loss

  auto cvt = [&](const float* src, unsigned short* dst, size_t n) {
    int n4 = (int)(n / 4);
    cvt_bf16<<<dim3((n4 + 255) / 256), dim3(256), 0, stream>>>(src, dst, n4);
  };

  // ---- convert inputs/weights to bf16 ----
  cvt(x,      xb,   4096ull * 512);
  cvt(W1,     W1b,  2048ull * 512);
  cvt(W2,     W2b,  128ull  * 2048);
  cvt(W3,     W3b,  512ull  * 128);
  cvt(head_W, hWb,  (size_t)HEADC * 512);
  cvt(t0a,    t0ab, 128ull  * 512);
  cvt(t0b,    t0bb, 8000ull * 128);
  cvt(t1a,    t1ab, 32ull   * 512);
  cvt(t1b,    t1bb, 40000ull* 32);

  const dim3 blk(256);

  // ---- MLP (bf16 MFMA): 512 -> 2048 -> 128 -> 512, ReLU each ----
  gemm_mfma<2, 2, true,  true ><<<dim3(2048/64, 4096/128), blk, 0, stream>>>(xb,  W1b, b1, H1b, 4096, 2048, 512);
  gemm_mfma<2, 2, true,  true ><<<dim3(128/64,  4096/128), blk, 0, stream>>>(H1b, W2b, b2, H2b, 4096, 128,  2048);
  gemm_mfma<2, 2, true,  true ><<<dim3(512/64,  4096/128), blk, 0, stream>>>(H2b, W3b, b3, Sb,  4096, 512,  128);

  // ---- tail low-rank projections ----
  gemm_mfma<2, 2, false, false><<<dim3(128/64,  4096/128), blk, 0, stream>>>(Sb, t0ab, nullptr, h0b, 4096, 128, 512);
  gemm_mfma<4, 1, false, false><<<dim3(1,       4096/256), blk, 0, stream>>>(Sb, t1ab, nullptr, h1b, 4096, 32,  512);

  // ---- fused MFMA + deferred-max LSE (exp2 domain) ----
  fused_lse<16, true ><<<dim3(64, 9),  blk, 0, stream>>>(Sb,  hWb,  head_b, HEADC,  14,  9,  pmh, psh);
  fused_lse<4,  false><<<dim3(64, 10), blk, 0, stream>>>(h0b, t0bb, nullptr, C0_CLS, 50, 10, pm0, ps0);
  fused_lse<1,  false><<<dim3(64, 25), blk, 0, stream>>>(h1b, t1bb, nullptr, C1_CLS, 100, 25, pm1, ps1);

  // ---- gathered logits (5 dots per row) ----
  gather_kernel<<<dim3(NROWS / 4), blk, 0, stream>>>(
      Sb, hWb, head_b, h0b, t0bb, h1b, t1bb, t, gsh, gc0, gc1, tg0, tg1);

  // ---- combine + loss ----
  combine_kernel<<<dim3((NROWS + 255) / 256), blk, 0, stream>>>(
      t, pmh, psh, gsh, gc0, gc1, pm0, ps0, tg0, pm1, ps1, tg1, out);
  loss_kernel<<<dim3(1), blk, 0, stream>>>(out, out + NROWS);
}

// Round 4
// 418.562 us; speedup vs baseline: 3.3523x; 1.0540x over previous
//
#include <hip/hip_runtime.h>
#include <math.h>

typedef __attribute__((ext_vector_type(8))) short bf16x8;
typedef __attribute__((ext_vector_type(4))) float f32x4;

#define NROWS 4096
#define SHORTLIST 2000
#define HEADC 2002
#define CUT1 10000
#define C0_CLS 8000
#define C1_CLS 40000
#define L2E 1.4426950408889634f
#define LN2 0.6931471805599453f

// partial-split counts
#define NH_P  14
#define NC0_P 25
#define NC1_P 50

__device__ __forceinline__ float fexp2(float x) {
#if __has_builtin(__builtin_amdgcn_exp2f)
  return __builtin_amdgcn_exp2f(x);
#else
  return exp2f(x);
#endif
}

__device__ __forceinline__ unsigned short f2b(float f) {
  unsigned u = __float_as_uint(f);
  unsigned r = (u + 0x7FFFu + ((u >> 16) & 1u)) >> 16;
  return (unsigned short)r;
}
__device__ __forceinline__ float b2f(unsigned short u) {
  return __uint_as_float(((unsigned)u) << 16);
}

// ---------------------------------------------------------------------------
// f32 -> bf16 (RNE), vectorized x4
// ---------------------------------------------------------------------------
__global__ __launch_bounds__(256) void cvt_bf16(const float* __restrict__ in,
                                                unsigned short* __restrict__ out,
                                                int n4) {
  int i = blockIdx.x * 256 + threadIdx.x;
  if (i >= n4) return;
  float4 v = ((const float4*)in)[i];
  ushort4 o;
  o.x = f2b(v.x); o.y = f2b(v.y); o.z = f2b(v.z); o.w = f2b(v.w);
  ((ushort4*)out)[i] = o;
}

// ---------------------------------------------------------------------------
// LDS-free MFMA GEMM: C_bf16[M,N] = act(A[M,K] @ W[N,K]^T + bias)
// Per-wave tile 64x32 (8 MFMAs per 6x16B loads). Block = WR x WC waves
// (WR*WC == 4): block tile (WR*64) x (WC*32). K % 32 == 0.
// ---------------------------------------------------------------------------
template<int WR, int WC, bool BIAS, bool RELU>
__global__ __launch_bounds__(256) void gemm_mfma(
    const unsigned short* __restrict__ A, const unsigned short* __restrict__ W,
    const float* __restrict__ bias, unsigned short* __restrict__ C,
    int M, int N, int K)
{
  const int lane = threadIdx.x & 63;
  const int wv   = threadIdx.x >> 6;
  const int cl   = lane & 15;
  const int ko   = lane >> 4;
  const int rw   = (blockIdx.y * WR + (wv / WC)) * 64;
  const int cw   = (blockIdx.x * WC + (wv % WC)) * 32;

  f32x4 acc[4][2];
#pragma unroll
  for (int p = 0; p < 4; ++p)
#pragma unroll
    for (int q = 0; q < 2; ++q) acc[p][q] = (f32x4){0.f, 0.f, 0.f, 0.f};

  const unsigned short* ap = A + (size_t)(rw + cl) * K + ko * 8;
  const unsigned short* bp = W + (size_t)(cw + cl) * K + ko * 8;
  const size_t rstep = (size_t)16 * K;

#pragma unroll 2
  for (int kb = 0; kb < K; kb += 32) {
    bf16x8 a[4], b[2];
#pragma unroll
    for (int p = 0; p < 4; ++p) a[p] = *(const bf16x8*)(ap + p * rstep + kb);
#pragma unroll
    for (int q = 0; q < 2; ++q) b[q] = *(const bf16x8*)(bp + q * rstep + kb);
#pragma unroll
    for (int p = 0; p < 4; ++p)
#pragma unroll
      for (int q = 0; q < 2; ++q)
        acc[p][q] = __builtin_amdgcn_mfma_f32_16x16x32_bf16(a[p], b[q], acc[p][q], 0, 0, 0);
  }

#pragma unroll
  for (int q = 0; q < 2; ++q) {
    const int col = cw + q * 16 + cl;
    float bs = 0.f;
    if (BIAS) bs = bias[col];
#pragma unroll
    for (int p = 0; p < 4; ++p) {
#pragma unroll
      for (int j = 0; j < 4; ++j) {
        const int R = rw + p * 16 + 4 * ko + j;
        float v = acc[p][q][j] + bs;
        if (RELU) v = fmaxf(v, 0.f);
        C[(size_t)R * N + col] = f2b(v);
      }
    }
  }
}

// ---------------------------------------------------------------------------
// Fused MFMA GEMV + deferred-max online LSE (exp2 domain, no LDS).
// Per wave: ROWT*16 rows. Per iteration: U class-chunks -> U*KBLK W-loads
// in flight, ROWT*U MFMAs per load batch, batched epilogue.
// pm/ps partials per (row, blockIdx.y): m in log2 units, s = sum 2^(v-m).
// ---------------------------------------------------------------------------
template<int KBLK, int ROWT, int U, bool HEAD>
__global__ __launch_bounds__(256) void fused_lse(
    const unsigned short* __restrict__ H,   // [NROWS][K] bf16
    const unsigned short* __restrict__ W,   // [C][K] bf16
    const float* __restrict__ bias,         // head only (f32)
    int C, int CPB, int NCB,
    float* __restrict__ pm, float* __restrict__ ps)
{
  const int K    = KBLK * 32;
  const int lane = threadIdx.x & 63;
  const int wv   = threadIdx.x >> 6;
  const int cl   = lane & 15;
  const int ko   = lane >> 4;
  const int r0   = blockIdx.x * (64 * ROWT) + wv * (16 * ROWT);

  bf16x8 aF[ROWT][KBLK];
#pragma unroll
  for (int rt = 0; rt < ROWT; ++rt) {
    const unsigned short* ap = H + (size_t)(r0 + rt * 16 + cl) * K + ko * 8;
#pragma unroll
    for (int kk = 0; kk < KBLK; ++kk) aF[rt][kk] = *(const bf16x8*)(ap + kk * 32);
  }

  float m[ROWT][4], s[ROWT][4];
#pragma unroll
  for (int rt = 0; rt < ROWT; ++rt)
#pragma unroll
    for (int j = 0; j < 4; ++j) { m[rt][j] = -1e30f; s[rt][j] = 0.f; }

  const int cb0 = blockIdx.y * CPB * 16;

  for (int it = 0; it < CPB / U; ++it) {
    const int cbase = cb0 + it * U * 16;

    bf16x8 bF[U][KBLK];
    int cc[U];
#pragma unroll
    for (int u = 0; u < U; ++u) {
      const int c = cbase + u * 16 + cl;
      cc[u] = c;
      const int crow = HEAD ? min(c, C - 1) : c;
      const unsigned short* wpc = W + (size_t)crow * K + ko * 8;
#pragma unroll
      for (int kk = 0; kk < KBLK; ++kk)
        bF[u][kk] = *(const bf16x8*)(wpc + kk * 32);
    }

    float bl2[U];
    if (HEAD) {
#pragma unroll
      for (int u = 0; u < U; ++u) bl2[u] = bias[min(cc[u], C - 1)] * L2E;
    }

    f32x4 acc[ROWT][U];
#pragma unroll
    for (int rt = 0; rt < ROWT; ++rt)
#pragma unroll
      for (int u = 0; u < U; ++u) acc[rt][u] = (f32x4){0.f, 0.f, 0.f, 0.f};

#pragma unroll
    for (int kk = 0; kk < KBLK; ++kk)
#pragma unroll
      for (int u = 0; u < U; ++u)
#pragma unroll
        for (int rt = 0; rt < ROWT; ++rt)
          acc[rt][u] = __builtin_amdgcn_mfma_f32_16x16x32_bf16(aF[rt][kk], bF[u][kk], acc[rt][u], 0, 0, 0);

    float v[ROWT][U][4];
    float dm[ROWT][4];
#pragma unroll
    for (int rt = 0; rt < ROWT; ++rt)
#pragma unroll
      for (int j = 0; j < 4; ++j) dm[rt][j] = -3e38f;

#pragma unroll
    for (int rt = 0; rt < ROWT; ++rt)
#pragma unroll
      for (int u = 0; u < U; ++u)
#pragma unroll
        for (int j = 0; j < 4; ++j) {
          float vv = HEAD ? fmaf(acc[rt][u][j], L2E, bl2[u])
                          : acc[rt][u][j] * L2E;
          if (HEAD && cc[u] >= C) vv = -1e30f;
          v[rt][u][j] = vv;
          dm[rt][j] = fmaxf(dm[rt][j], vv);
        }

    float dd = -3e38f;
#pragma unroll
    for (int rt = 0; rt < ROWT; ++rt)
#pragma unroll
      for (int j = 0; j < 4; ++j) dd = fmaxf(dd, dm[rt][j] - m[rt][j]);

    if (__any(dd > 8.f)) {
#pragma unroll
      for (int rt = 0; rt < ROWT; ++rt)
#pragma unroll
        for (int j = 0; j < 4; ++j) {
          const float mn = fmaxf(m[rt][j], dm[rt][j]);
          s[rt][j] *= fexp2(m[rt][j] - mn);
          m[rt][j] = mn;
        }
    }
#pragma unroll
    for (int rt = 0; rt < ROWT; ++rt)
#pragma unroll
      for (int u = 0; u < U; ++u)
#pragma unroll
        for (int j = 0; j < 4; ++j)
          s[rt][j] += fexp2(v[rt][u][j] - m[rt][j]);
  }

  // reduce (m,s) across the 16 class-lanes
#pragma unroll
  for (int mask = 1; mask <= 8; mask <<= 1) {
#pragma unroll
    for (int rt = 0; rt < ROWT; ++rt)
#pragma unroll
      for (int j = 0; j < 4; ++j) {
        const float mo = __shfl_xor(m[rt][j], mask);
        const float so = __shfl_xor(s[rt][j], mask);
        const float mn = fmaxf(m[rt][j], mo);
        s[rt][j] = s[rt][j] * fexp2(m[rt][j] - mn) + so * fexp2(mo - mn);
        m[rt][j] = mn;
      }
  }
  if (cl == 0) {
#pragma unroll
    for (int rt = 0; rt < ROWT; ++rt)
#pragma unroll
      for (int j = 0; j < 4; ++j) {
        const int R = r0 + rt * 16 + 4 * ko + j;
        pm[(size_t)R * NCB + blockIdx.y] = m[rt][j];
        ps[(size_t)R * NCB + blockIdx.y] = s[rt][j];
      }
  }
}

// ---------------------------------------------------------------------------
// Target / cluster-logit gather: per row the 5 needed raw logits as dots.
// One 64-lane wave per row (4 rows / block).
// ---------------------------------------------------------------------------
__global__ __launch_bounds__(256) void gather_kernel(
    const unsigned short* __restrict__ Sb,   // [4096][512]
    const unsigned short* __restrict__ hWb,  // [2002][512]
    const float* __restrict__ head_b,
    const unsigned short* __restrict__ h0b,  // [4096][128]
    const unsigned short* __restrict__ t0bb, // [8000][128]
    const unsigned short* __restrict__ h1b,  // [4096][32]
    const unsigned short* __restrict__ t1bb, // [40000][32]
    const int* __restrict__ t,
    float* __restrict__ gsh, float* __restrict__ gc0, float* __restrict__ gc1,
    float* __restrict__ tg0, float* __restrict__ tg1)
{
  const int lane = threadIdx.x & 63;
  const int row  = blockIdx.x * 4 + (threadIdx.x >> 6);
  const int tv   = t[row];
  const int ch   = min(max(tv, 0), SHORTLIST - 1);
  const int c0   = min(max(tv - SHORTLIST, 0), C0_CLS - 1);
  const int c1   = min(max(tv - CUT1, 0), C1_CLS - 1);

  float acc[5] = {0.f, 0.f, 0.f, 0.f, 0.f};

  {
    bf16x8 sv = *(const bf16x8*)(Sb + (size_t)row * 512 + lane * 8);
    bf16x8 w0 = *(const bf16x8*)(hWb + (size_t)ch * 512 + lane * 8);
    bf16x8 w1 = *(const bf16x8*)(hWb + (size_t)SHORTLIST * 512 + lane * 8);
    bf16x8 w2 = *(const bf16x8*)(hWb + (size_t)(SHORTLIST + 1) * 512 + lane * 8);
#pragma unroll
    for (int e = 0; e < 8; ++e) {
      const float sf = b2f((unsigned short)sv[e]);
      acc[0] = fmaf(sf, b2f((unsigned short)w0[e]), acc[0]);
      acc[1] = fmaf(sf, b2f((unsigned short)w1[e]), acc[1]);
      acc[2] = fmaf(sf, b2f((unsigned short)w2[e]), acc[2]);
    }
  }
  if (lane < 16) {
    bf16x8 hv = *(const bf16x8*)(h0b + (size_t)row * 128 + lane * 8);
    bf16x8 wv = *(const bf16x8*)(t0bb + (size_t)c0 * 128 + lane * 8);
#pragma unroll
    for (int e = 0; e < 8; ++e)
      acc[3] = fmaf(b2f((unsigned short)hv[e]), b2f((unsigned short)wv[e]), acc[3]);
  }
  if (lane < 4) {
    bf16x8 hv = *(const bf16x8*)(h1b + (size_t)row * 32 + lane * 8);
    bf16x8 wv = *(const bf16x8*)(t1bb + (size_t)c1 * 32 + lane * 8);
#pragma unroll
    for (int e = 0; e < 8; ++e)
      acc[4] = fmaf(b2f((unsigned short)hv[e]), b2f((unsigned short)wv[e]), acc[4]);
  }

#pragma unroll
  for (int mask = 1; mask < 64; mask <<= 1)
#pragma unroll
    for (int k = 0; k < 5; ++k) acc[k] += __shfl_xor(acc[k], mask);

  if (lane == 0) {
    gsh[row] = acc[0] + head_b[ch];
    gc0[row] = acc[1] + head_b[SHORTLIST];
    gc1[row] = acc[2] + head_b[SHORTLIST + 1];
    tg0[row] = acc[3];
    tg1[row] = acc[4];
  }
}

// ---------------------------------------------------------------------------
// Combine partials (log2 domain) into out[row]
// ---------------------------------------------------------------------------
__global__ __launch_bounds__(256) void combine_kernel(
    const int* __restrict__ t,
    const float* __restrict__ pmh, const float* __restrict__ psh,
    const float* __restrict__ gsh, const float* __restrict__ gc0,
    const float* __restrict__ gc1,
    const float* __restrict__ pm0, const float* __restrict__ ps0,
    const float* __restrict__ tg0,
    const float* __restrict__ pm1, const float* __restrict__ ps1,
    const float* __restrict__ tg1,
    float* __restrict__ out)
{
  const int r = blockIdx.x * 256 + threadIdx.x;
  if (r >= NROWS) return;

  float M = -1e30f, S = 0.f;
  for (int c = 0; c < NH_P; ++c) M = fmaxf(M, pmh[r * NH_P + c]);
  for (int c = 0; c < NH_P; ++c) S += psh[r * NH_P + c] * fexp2(pmh[r * NH_P + c] - M);
  const float hl = (M + log2f(S)) * LN2;

  const int tv = t[r];
  float o;
  if (tv < SHORTLIST) {
    o = gsh[r] - hl;
  } else if (tv < CUT1) {
    float M0 = -1e30f, S0 = 0.f;
    for (int c = 0; c < NC0_P; ++c) M0 = fmaxf(M0, pm0[r * NC0_P + c]);
    for (int c = 0; c < NC0_P; ++c) S0 += ps0[r * NC0_P + c] * fexp2(pm0[r * NC0_P + c] - M0);
    o = (gc0[r] - hl) + (tg0[r] - (M0 + log2f(S0)) * LN2);
  } else {
    float M1 = -1e30f, S1 = 0.f;
    for (int c = 0; c < NC1_P; ++c) M1 = fmaxf(M1, pm1[r * NC1_P + c]);
    for (int c = 0; c < NC1_P; ++c) S1 += ps1[r * NC1_P + c] * fexp2(pm1[r * NC1_P + c] - M1);
    o = (gc1[r] - hl) + (tg1[r] - (M1 + log2f(S1)) * LN2);
  }
  out[r] = o;
}

__global__ __launch_bounds__(256) void loss_kernel(
    const float* __restrict__ out, float* __restrict__ loss)
{
  __shared__ float sred[256];
  const int tid = threadIdx.x;
  float s = 0.f;
  for (int i = tid; i < NROWS; i += 256) s += out[i];
  sred[tid] = s;
  __syncthreads();
  for (int st = 128; st > 0; st >>= 1) {
    if (tid < st) sred[tid] += sred[tid + st];
    __syncthreads();
  }
  if (tid == 0) *loss = -sred[0] / (float)NROWS;
}

// ---------------------------------------------------------------------------
extern "C" void kernel_launch(void* const* d_in, const int* in_sizes, int n_in,
                              void* d_out, int out_size, void* d_ws, size_t ws_size,
                              hipStream_t stream)
{
  const float* x      = (const float*)d_in[0];
  const int*   t      = (const int*)  d_in[1];
  const float* W1     = (const float*)d_in[2];
  const float* b1     = (const float*)d_in[3];
  const float* W2     = (const float*)d_in[4];
  const float* b2     = (const float*)d_in[5];
  const float* W3     = (const float*)d_in[6];
  const float* b3     = (const float*)d_in[7];
  const float* head_W = (const float*)d_in[8];
  const float* head_b = (const float*)d_in[9];
  const float* t0a    = (const float*)d_in[10];
  const float* t0b    = (const float*)d_in[11];
  const float* t1a    = (const float*)d_in[12];
  const float* t1b    = (const float*)d_in[13];

  // ---- workspace layout (bf16 region, then f32 region) ----
  unsigned short* p16 = (unsigned short*)d_ws;
  unsigned short* xb  = p16; p16 += 4096ull * 512;
  unsigned short* W1b = p16; p16 += 2048ull * 512;
  unsigned short* W2b = p16; p16 += 128ull  * 2048;
  unsigned short* W3b = p16; p16 += 512ull  * 128;
  unsigned short* hWb = p16; p16 += (size_t)HEADC * 512;
  unsigned short* t0ab= p16; p16 += 128ull  * 512;
  unsigned short* t0bb= p16; p16 += 8000ull * 128;
  unsigned short* t1ab= p16; p16 += 32ull   * 512;
  unsigned short* t1bb= p16; p16 += 40000ull* 32;
  unsigned short* H1b = p16; p16 += 4096ull * 2048;
  unsigned short* H2b = p16; p16 += 4096ull * 128;
  unsigned short* Sb  = p16; p16 += 4096ull * 512;
  unsigned short* h0b = p16; p16 += 4096ull * 128;
  unsigned short* h1b = p16; p16 += 4096ull * 32;

  float* pf  = (float*)p16;
  float* pmh = pf; pf += 4096 * NH_P;
  float* psh = pf; pf += 4096 * NH_P;
  float* pm0 = pf; pf += 4096 * NC0_P;
  float* ps0 = pf; pf += 4096 * NC0_P;
  float* pm1 = pf; pf += 4096 * NC1_P;
  float* ps1 = pf; pf += 4096 * NC1_P;
  float* gsh = pf; pf += 4096;
  float* gc0 = pf; pf += 4096;
  float* gc1 = pf; pf += 4096;
  float* tg0 = pf; pf += 4096;
  float* tg1 = pf; pf += 4096;

  float* out = (float*)d_out;   // [4096] log-probs, then [1] loss

  auto cvt = [&](const float* src, unsigned short* dst, size_t n) {
    int n4 = (int)(n / 4);
    cvt_bf16<<<dim3((n4 + 255) / 256), dim3(256), 0, stream>>>(src, dst, n4);
  };

  // ---- convert inputs/weights to bf16 ----
  cvt(x,      xb,   4096ull * 512);
  cvt(W1,     W1b,  2048ull * 512);
  cvt(W2,     W2b,  128ull  * 2048);
  cvt(W3,     W3b,  512ull  * 128);
  cvt(head_W, hWb,  (size_t)HEADC * 512);
  cvt(t0a,    t0ab, 128ull  * 512);
  cvt(t0b,    t0bb, 8000ull * 128);
  cvt(t1a,    t1ab, 32ull   * 512);
  cvt(t1b,    t1bb, 40000ull* 32);

  const dim3 blk(256);

  // ---- MLP (bf16 MFMA): 512 -> 2048 -> 128 -> 512, ReLU each ----
  gemm_mfma<2, 2, true,  true ><<<dim3(2048/64, 4096/128), blk, 0, stream>>>(xb,  W1b, b1, H1b, 4096, 2048, 512);
  gemm_mfma<2, 2, true,  true ><<<dim3(128/64,  4096/128), blk, 0, stream>>>(H1b, W2b, b2, H2b, 4096, 128,  2048);
  gemm_mfma<2, 2, true,  true ><<<dim3(512/64,  4096/128), blk, 0, stream>>>(H2b, W3b, b3, Sb,  4096, 512,  128);

  // ---- tail low-rank projections ----
  gemm_mfma<2, 2, false, false><<<dim3(128/64,  4096/128), blk, 0, stream>>>(Sb, t0ab, nullptr, h0b, 4096, 128, 512);
  gemm_mfma<4, 1, false, false><<<dim3(1,       4096/256), blk, 0, stream>>>(Sb, t1ab, nullptr, h1b, 4096, 32,  512);

  // ---- fused MFMA + deferred-max LSE (exp2 domain) ----
  // head:  126 chunks = 14 blocks x 9,  ROWT=1 (KBLK=16 gives load ILP)
  // tail0: 500 chunks = 25 blocks x 20, ROWT=2, U=2 (8 loads in flight)
  // tail1: 2500 chunks = 50 blocks x 50, ROWT=2, U=5 (5 loads in flight)
  fused_lse<16, 1, 1, true ><<<dim3(64, NH_P),  blk, 0, stream>>>(Sb,  hWb,  head_b, HEADC,  9,  NH_P,  pmh, psh);
  fused_lse<4,  2, 2, false><<<dim3(32, NC0_P), blk, 0, stream>>>(h0b, t0bb, nullptr, C0_CLS, 20, NC0_P, pm0, ps0);
  fused_lse<1,  2, 5, false><<<dim3(32, NC1_P), blk, 0, stream>>>(h1b, t1bb, nullptr, C1_CLS, 50, NC1_P, pm1, ps1);

  // ---- gathered logits (5 dots per row) ----
  gather_kernel<<<dim3(NROWS / 4), blk, 0, stream>>>(
      Sb, hWb, head_b, h0b, t0bb, h1b, t1bb, t, gsh, gc0, gc1, tg0, tg1);

  // ---- combine + loss ----
  combine_kernel<<<dim3((NROWS + 255) / 256), blk, 0, stream>>>(
      t, pmh, psh, gsh, gc0, gc1, pm0, ps0, tg0, pm1, ps1, tg1, out);
  loss_kernel<<<dim3(1), blk, 0, stream>>>(out, out + NROWS);
}

// Round 5
// 389.807 us; speedup vs baseline: 3.5996x; 1.0738x over previous
//
#include <hip/hip_runtime.h>
#include <math.h>

typedef __attribute__((ext_vector_type(8))) short bf16x8;
typedef __attribute__((ext_vector_type(4))) float f32x4;

#define NROWS 4096
#define SHORTLIST 2000
#define HEADC 2002
#define CUT1 10000
#define C0_CLS 8000
#define C1_CLS 40000
#define L2E 1.4426950408889634f
#define LN2 0.6931471805599453f

// partial-split counts
#define NH_P  32
#define NC0_P 25
#define NC1_P 125

__device__ __forceinline__ float fexp2(float x) {
#if __has_builtin(__builtin_amdgcn_exp2f)
  return __builtin_amdgcn_exp2f(x);
#else
  return exp2f(x);
#endif
}

__device__ __forceinline__ unsigned short f2b(float f) {
  unsigned u = __float_as_uint(f);
  unsigned r = (u + 0x7FFFu + ((u >> 16) & 1u)) >> 16;
  return (unsigned short)r;
}
__device__ __forceinline__ float b2f(unsigned short u) {
  return __uint_as_float(((unsigned)u) << 16);
}

// ---------------------------------------------------------------------------
// All f32->bf16 conversions in ONE launch. blockIdx.y selects the segment,
// blockIdx.x grid-strides within it.
// ---------------------------------------------------------------------------
__global__ __launch_bounds__(256) void cvt_all(
    const float* __restrict__ s0, unsigned short* __restrict__ d0,  // x
    const float* __restrict__ s1, unsigned short* __restrict__ d1,  // W1
    const float* __restrict__ s2, unsigned short* __restrict__ d2,  // W2
    const float* __restrict__ s3, unsigned short* __restrict__ d3,  // W3
    const float* __restrict__ s4, unsigned short* __restrict__ d4,  // head_W
    const float* __restrict__ s5, unsigned short* __restrict__ d5,  // t0a
    const float* __restrict__ s6, unsigned short* __restrict__ d6,  // t0b
    const float* __restrict__ s7, unsigned short* __restrict__ d7,  // t1a
    const float* __restrict__ s8, unsigned short* __restrict__ d8)  // t1b
{
  const float* src; unsigned short* dst; int n4;
  switch (blockIdx.y) {
    case 0: src = s0; dst = d0; n4 = 4096 * 512 / 4;   break;
    case 1: src = s1; dst = d1; n4 = 2048 * 512 / 4;   break;
    case 2: src = s2; dst = d2; n4 = 128 * 2048 / 4;   break;
    case 3: src = s3; dst = d3; n4 = 512 * 128 / 4;    break;
    case 4: src = s4; dst = d4; n4 = HEADC * 512 / 4;  break;
    case 5: src = s5; dst = d5; n4 = 128 * 512 / 4;    break;
    case 6: src = s6; dst = d6; n4 = 8000 * 128 / 4;   break;
    case 7: src = s7; dst = d7; n4 = 32 * 512 / 4;     break;
    default: src = s8; dst = d8; n4 = 40000 * 32 / 4;  break;
  }
  for (int i = blockIdx.x * 256 + threadIdx.x; i < n4; i += 256 * gridDim.x) {
    float4 v = ((const float4*)src)[i];
    ushort4 o;
    o.x = f2b(v.x); o.y = f2b(v.y); o.z = f2b(v.z); o.w = f2b(v.w);
    ((ushort4*)dst)[i] = o;
  }
}

// ---------------------------------------------------------------------------
// LDS-free MFMA GEMM: C_bf16[M,N] = act(A[M,K] @ W[N,K]^T + bias)
// Per-wave tile 64x32. Block = WR x WC waves (WR*WC == 4). K % 32 == 0.
// ---------------------------------------------------------------------------
template<int WR, int WC, bool BIAS, bool RELU>
__global__ __launch_bounds__(256) void gemm_mfma(
    const unsigned short* __restrict__ A, const unsigned short* __restrict__ W,
    const float* __restrict__ bias, unsigned short* __restrict__ C,
    int M, int N, int K)
{
  const int lane = threadIdx.x & 63;
  const int wv   = threadIdx.x >> 6;
  const int cl   = lane & 15;
  const int ko   = lane >> 4;
  const int rw   = (blockIdx.y * WR + (wv / WC)) * 64;
  const int cw   = (blockIdx.x * WC + (wv % WC)) * 32;

  f32x4 acc[4][2];
#pragma unroll
  for (int p = 0; p < 4; ++p)
#pragma unroll
    for (int q = 0; q < 2; ++q) acc[p][q] = (f32x4){0.f, 0.f, 0.f, 0.f};

  const unsigned short* ap = A + (size_t)(rw + cl) * K + ko * 8;
  const unsigned short* bp = W + (size_t)(cw + cl) * K + ko * 8;
  const size_t rstep = (size_t)16 * K;

#pragma unroll 2
  for (int kb = 0; kb < K; kb += 32) {
    bf16x8 a[4], b[2];
#pragma unroll
    for (int p = 0; p < 4; ++p) a[p] = *(const bf16x8*)(ap + p * rstep + kb);
#pragma unroll
    for (int q = 0; q < 2; ++q) b[q] = *(const bf16x8*)(bp + q * rstep + kb);
#pragma unroll
    for (int p = 0; p < 4; ++p)
#pragma unroll
      for (int q = 0; q < 2; ++q)
        acc[p][q] = __builtin_amdgcn_mfma_f32_16x16x32_bf16(a[p], b[q], acc[p][q], 0, 0, 0);
  }

#pragma unroll
  for (int q = 0; q < 2; ++q) {
    const int col = cw + q * 16 + cl;
    float bs = 0.f;
    if (BIAS) bs = bias[col];
#pragma unroll
    for (int p = 0; p < 4; ++p) {
#pragma unroll
      for (int j = 0; j < 4; ++j) {
        const int R = rw + p * 16 + 4 * ko + j;
        float v = acc[p][q][j] + bs;
        if (RELU) v = fmaxf(v, 0.f);
        C[(size_t)R * N + col] = f2b(v);
      }
    }
  }
}

// ---------------------------------------------------------------------------
// Head: GEMM (128x64 block tile, 64x32 per wave) with fused per-row LSE
// epilogue over this block's 64 cols. Partials pm/ps [NH_P][NROWS] (log2).
// W has 2048 rows addressable; rows >= 2002 are garbage and masked here.
// ---------------------------------------------------------------------------
__global__ __launch_bounds__(256) void head_gemm_lse(
    const unsigned short* __restrict__ A,   // Sb [4096][512]
    const unsigned short* __restrict__ W,   // hWb (2048 rows span, 2002 valid)
    const float* __restrict__ bias,         // head_b [2002]
    float* __restrict__ pm, float* __restrict__ ps)
{
  const int K    = 512;
  const int lane = threadIdx.x & 63;
  const int wv   = threadIdx.x >> 6;
  const int cl   = lane & 15;
  const int ko   = lane >> 4;
  const int rw   = blockIdx.y * 128 + (wv >> 1) * 64;
  const int cw   = blockIdx.x * 64 + (wv & 1) * 32;

  f32x4 acc[4][2];
#pragma unroll
  for (int p = 0; p < 4; ++p)
#pragma unroll
    for (int q = 0; q < 2; ++q) acc[p][q] = (f32x4){0.f, 0.f, 0.f, 0.f};

  const unsigned short* ap = A + (size_t)(rw + cl) * K + ko * 8;
  const unsigned short* bp = W + (size_t)(cw + cl) * K + ko * 8;
  const size_t rstep = (size_t)16 * K;

#pragma unroll 2
  for (int kb = 0; kb < K; kb += 32) {
    bf16x8 a[4], b[2];
#pragma unroll
    for (int p = 0; p < 4; ++p) a[p] = *(const bf16x8*)(ap + p * rstep + kb);
#pragma unroll
    for (int q = 0; q < 2; ++q) b[q] = *(const bf16x8*)(bp + q * rstep + kb);
#pragma unroll
    for (int p = 0; p < 4; ++p)
#pragma unroll
      for (int q = 0; q < 2; ++q)
        acc[p][q] = __builtin_amdgcn_mfma_f32_16x16x32_bf16(a[p], b[q], acc[p][q], 0, 0, 0);
  }

  // ---- fused LSE epilogue (log2 domain) ----
  float bl2[2]; int colv[2];
#pragma unroll
  for (int q = 0; q < 2; ++q) {
    const int col = cw + q * 16 + cl;
    colv[q] = col;
    bl2[q] = bias[min(col, HEADC - 1)] * L2E;
  }

  float mr[4][4], sr[4][4];
#pragma unroll
  for (int p = 0; p < 4; ++p)
#pragma unroll
    for (int j = 0; j < 4; ++j) {
      float v0 = fmaf(acc[p][0][j], L2E, bl2[0]);
      float v1 = fmaf(acc[p][1][j], L2E, bl2[1]);
      if (colv[0] >= HEADC) v0 = -1e30f;
      if (colv[1] >= HEADC) v1 = -1e30f;
      const float mm = fmaxf(v0, v1);
      mr[p][j] = mm;
      sr[p][j] = fexp2(v0 - mm) + fexp2(v1 - mm);
    }

#pragma unroll
  for (int mask = 1; mask <= 8; mask <<= 1) {
#pragma unroll
    for (int p = 0; p < 4; ++p)
#pragma unroll
      for (int j = 0; j < 4; ++j) {
        const float mo = __shfl_xor(mr[p][j], mask);
        const float so = __shfl_xor(sr[p][j], mask);
        const float mn = fmaxf(mr[p][j], mo);
        sr[p][j] = sr[p][j] * fexp2(mr[p][j] - mn) + so * fexp2(mo - mn);
        mr[p][j] = mn;
      }
  }

  __shared__ float lm[4][64], ls[4][64];
  if (cl == 0) {
#pragma unroll
    for (int p = 0; p < 4; ++p)
#pragma unroll
      for (int j = 0; j < 4; ++j) {
        lm[wv][p * 16 + 4 * ko + j] = mr[p][j];
        ls[wv][p * 16 + 4 * ko + j] = sr[p][j];
      }
  }
  __syncthreads();
  const int tid = threadIdx.x;
  if (tid < 128) {
    const int pair = tid >> 6, idx = tid & 63;
    const float m0 = lm[pair * 2][idx],     m1 = lm[pair * 2 + 1][idx];
    const float M  = fmaxf(m0, m1);
    const float S  = ls[pair * 2][idx] * fexp2(m0 - M) + ls[pair * 2 + 1][idx] * fexp2(m1 - M);
    const int grow = blockIdx.y * 128 + tid;
    pm[(size_t)blockIdx.x * NROWS + grow] = M;
    ps[(size_t)blockIdx.x * NROWS + grow] = S;
  }
}

// ---------------------------------------------------------------------------
// Tail fused GEMV + deferred-max online LSE, double-buffered W prefetch.
// CPB = U*NIT chunks per y-block (NIT must be even). Partials [NCB][NROWS].
// ---------------------------------------------------------------------------
template<int KBLK, int ROWT, int U, int NIT>
__global__ __launch_bounds__(256) void fused_lse_tail(
    const unsigned short* __restrict__ H,   // [NROWS][K]
    const unsigned short* __restrict__ W,   // [C][K]
    int NCB,
    float* __restrict__ pm, float* __restrict__ ps)
{
  const int K    = KBLK * 32;
  const int lane = threadIdx.x & 63;
  const int wv   = threadIdx.x >> 6;
  const int cl   = lane & 15;
  const int ko   = lane >> 4;
  const int r0   = blockIdx.x * (64 * ROWT) + wv * (16 * ROWT);

  bf16x8 aF[ROWT][KBLK];
#pragma unroll
  for (int rt = 0; rt < ROWT; ++rt) {
    const unsigned short* ap = H + (size_t)(r0 + rt * 16 + cl) * K + ko * 8;
#pragma unroll
    for (int kk = 0; kk < KBLK; ++kk) aF[rt][kk] = *(const bf16x8*)(ap + kk * 32);
  }

  float m[ROWT][4], s[ROWT][4];
#pragma unroll
  for (int rt = 0; rt < ROWT; ++rt)
#pragma unroll
    for (int j = 0; j < 4; ++j) { m[rt][j] = -1e30f; s[rt][j] = 0.f; }

  const unsigned short* wbase =
      W + (size_t)(blockIdx.y * (U * NIT) * 16 + cl) * K + ko * 8;
  const size_t chunkstep = (size_t)16 * K;

  bf16x8 bA[U][KBLK], bB[U][KBLK];

  auto loadB = [&](bf16x8 (&bf)[U][KBLK], int it) {
    const unsigned short* p = wbase + (size_t)it * U * chunkstep;
#pragma unroll
    for (int u = 0; u < U; ++u)
#pragma unroll
      for (int kk = 0; kk < KBLK; ++kk)
        bf[u][kk] = *(const bf16x8*)(p + u * chunkstep + kk * 32);
  };

  auto consume = [&](bf16x8 (&bf)[U][KBLK]) {
    f32x4 acc[ROWT][U];
#pragma unroll
    for (int rt = 0; rt < ROWT; ++rt)
#pragma unroll
      for (int u = 0; u < U; ++u) acc[rt][u] = (f32x4){0.f, 0.f, 0.f, 0.f};
#pragma unroll
    for (int kk = 0; kk < KBLK; ++kk)
#pragma unroll
      for (int u = 0; u < U; ++u)
#pragma unroll
        for (int rt = 0; rt < ROWT; ++rt)
          acc[rt][u] = __builtin_amdgcn_mfma_f32_16x16x32_bf16(aF[rt][kk], bf[u][kk], acc[rt][u], 0, 0, 0);

    float nm[ROWT][4];
#pragma unroll
    for (int rt = 0; rt < ROWT; ++rt)
#pragma unroll
      for (int j = 0; j < 4; ++j) nm[rt][j] = m[rt][j];
#pragma unroll
    for (int rt = 0; rt < ROWT; ++rt)
#pragma unroll
      for (int u = 0; u < U; ++u)
#pragma unroll
        for (int j = 0; j < 4; ++j)
          nm[rt][j] = fmaxf(nm[rt][j], acc[rt][u][j] * L2E);

    float dd = -3e38f;
#pragma unroll
    for (int rt = 0; rt < ROWT; ++rt)
#pragma unroll
      for (int j = 0; j < 4; ++j) dd = fmaxf(dd, nm[rt][j] - m[rt][j]);

    if (__any(dd > 8.f)) {
#pragma unroll
      for (int rt = 0; rt < ROWT; ++rt)
#pragma unroll
        for (int j = 0; j < 4; ++j) {
          s[rt][j] *= fexp2(m[rt][j] - nm[rt][j]);
          m[rt][j] = nm[rt][j];
        }
    }
#pragma unroll
    for (int rt = 0; rt < ROWT; ++rt)
#pragma unroll
      for (int u = 0; u < U; ++u)
#pragma unroll
        for (int j = 0; j < 4; ++j)
          s[rt][j] += fexp2(fmaf(acc[rt][u][j], L2E, -m[rt][j]));
  };

  loadB(bA, 0);
#pragma unroll
  for (int it = 0; it < NIT; it += 2) {
    loadB(bB, it + 1);               // NIT even -> always valid
    consume(bA);
    if (it + 2 < NIT) loadB(bA, it + 2);
    consume(bB);
  }

  // reduce (m,s) across the 16 class-lanes
#pragma unroll
  for (int mask = 1; mask <= 8; mask <<= 1) {
#pragma unroll
    for (int rt = 0; rt < ROWT; ++rt)
#pragma unroll
      for (int j = 0; j < 4; ++j) {
        const float mo = __shfl_xor(m[rt][j], mask);
        const float so = __shfl_xor(s[rt][j], mask);
        const float mn = fmaxf(m[rt][j], mo);
        s[rt][j] = s[rt][j] * fexp2(m[rt][j] - mn) + so * fexp2(mo - mn);
        m[rt][j] = mn;
      }
  }
  if (cl == 0) {
#pragma unroll
    for (int rt = 0; rt < ROWT; ++rt)
#pragma unroll
      for (int j = 0; j < 4; ++j) {
        const int R = r0 + rt * 16 + 4 * ko + j;
        pm[(size_t)blockIdx.y * NROWS + R] = m[rt][j];
        ps[(size_t)blockIdx.y * NROWS + R] = s[rt][j];
      }
  }
}

// ---------------------------------------------------------------------------
// Target / cluster-logit gather: per row the 5 needed raw logits as dots.
// ---------------------------------------------------------------------------
__global__ __launch_bounds__(256) void gather_kernel(
    const unsigned short* __restrict__ Sb,   // [4096][512]
    const unsigned short* __restrict__ hWb,  // [2002][512]
    const float* __restrict__ head_b,
    const unsigned short* __restrict__ h0b,  // [4096][128]
    const unsigned short* __restrict__ t0bb, // [8000][128]
    const unsigned short* __restrict__ h1b,  // [4096][32]
    const unsigned short* __restrict__ t1bb, // [40000][32]
    const int* __restrict__ t,
    float* __restrict__ gsh, float* __restrict__ gc0, float* __restrict__ gc1,
    float* __restrict__ tg0, float* __restrict__ tg1)
{
  const int lane = threadIdx.x & 63;
  const int row  = blockIdx.x * 4 + (threadIdx.x >> 6);
  const int tv   = t[row];
  const int ch   = min(max(tv, 0), SHORTLIST - 1);
  const int c0   = min(max(tv - SHORTLIST, 0), C0_CLS - 1);
  const int c1   = min(max(tv - CUT1, 0), C1_CLS - 1);

  float acc[5] = {0.f, 0.f, 0.f, 0.f, 0.f};

  {
    bf16x8 sv = *(const bf16x8*)(Sb + (size_t)row * 512 + lane * 8);
    bf16x8 w0 = *(const bf16x8*)(hWb + (size_t)ch * 512 + lane * 8);
    bf16x8 w1 = *(const bf16x8*)(hWb + (size_t)SHORTLIST * 512 + lane * 8);
    bf16x8 w2 = *(const bf16x8*)(hWb + (size_t)(SHORTLIST + 1) * 512 + lane * 8);
#pragma unroll
    for (int e = 0; e < 8; ++e) {
      const float sf = b2f((unsigned short)sv[e]);
      acc[0] = fmaf(sf, b2f((unsigned short)w0[e]), acc[0]);
      acc[1] = fmaf(sf, b2f((unsigned short)w1[e]), acc[1]);
      acc[2] = fmaf(sf, b2f((unsigned short)w2[e]), acc[2]);
    }
  }
  if (lane < 16) {
    bf16x8 hv = *(const bf16x8*)(h0b + (size_t)row * 128 + lane * 8);
    bf16x8 wv = *(const bf16x8*)(t0bb + (size_t)c0 * 128 + lane * 8);
#pragma unroll
    for (int e = 0; e < 8; ++e)
      acc[3] = fmaf(b2f((unsigned short)hv[e]), b2f((unsigned short)wv[e]), acc[3]);
  }
  if (lane < 4) {
    bf16x8 hv = *(const bf16x8*)(h1b + (size_t)row * 32 + lane * 8);
    bf16x8 wv = *(const bf16x8*)(t1bb + (size_t)c1 * 32 + lane * 8);
#pragma unroll
    for (int e = 0; e < 8; ++e)
      acc[4] = fmaf(b2f((unsigned short)hv[e]), b2f((unsigned short)wv[e]), acc[4]);
  }

#pragma unroll
  for (int mask = 1; mask < 64; mask <<= 1)
#pragma unroll
    for (int k = 0; k < 5; ++k) acc[k] += __shfl_xor(acc[k], mask);

  if (lane == 0) {
    gsh[row] = acc[0] + head_b[ch];
    gc0[row] = acc[1] + head_b[SHORTLIST];
    gc1[row] = acc[2] + head_b[SHORTLIST + 1];
    tg0[row] = acc[3];
    tg1[row] = acc[4];
  }
}

// ---------------------------------------------------------------------------
// Combine partials (log2 domain, [NCB][NROWS] layout) into out[row]
// ---------------------------------------------------------------------------
__global__ __launch_bounds__(256) void combine_kernel(
    const int* __restrict__ t,
    const float* __restrict__ pmh, const float* __restrict__ psh,
    const float* __restrict__ gsh, const float* __restrict__ gc0,
    const float* __restrict__ gc1,
    const float* __restrict__ pm0, const float* __restrict__ ps0,
    const float* __restrict__ tg0,
    const float* __restrict__ pm1, const float* __restrict__ ps1,
    const float* __restrict__ tg1,
    float* __restrict__ out)
{
  const int r = blockIdx.x * 256 + threadIdx.x;
  if (r >= NROWS) return;

  float M = -1e30f, S = 0.f;
  for (int c = 0; c < NH_P; ++c) M = fmaxf(M, pmh[c * NROWS + r]);
  for (int c = 0; c < NH_P; ++c) S += psh[c * NROWS + r] * fexp2(pmh[c * NROWS + r] - M);
  const float hl = (M + log2f(S)) * LN2;

  const int tv = t[r];
  float o;
  if (tv < SHORTLIST) {
    o = gsh[r] - hl;
  } else if (tv < CUT1) {
    float M0 = -1e30f, S0 = 0.f;
    for (int c = 0; c < NC0_P; ++c) M0 = fmaxf(M0, pm0[c * NROWS + r]);
    for (int c = 0; c < NC0_P; ++c) S0 += ps0[c * NROWS + r] * fexp2(pm0[c * NROWS + r] - M0);
    o = (gc0[r] - hl) + (tg0[r] - (M0 + log2f(S0)) * LN2);
  } else {
    float M1 = -1e30f, S1 = 0.f;
    for (int c = 0; c < NC1_P; ++c) M1 = fmaxf(M1, pm1[c * NROWS + r]);
    for (int c = 0; c < NC1_P; ++c) S1 += ps1[c * NROWS + r] * fexp2(pm1[c * NROWS + r] - M1);
    o = (gc1[r] - hl) + (tg1[r] - (M1 + log2f(S1)) * LN2);
  }
  out[r] = o;
}

__global__ __launch_bounds__(256) void loss_kernel(
    const float* __restrict__ out, float* __restrict__ loss)
{
  __shared__ float sred[256];
  const int tid = threadIdx.x;
  float s = 0.f;
  for (int i = tid; i < NROWS; i += 256) s += out[i];
  sred[tid] = s;
  __syncthreads();
  for (int st = 128; st > 0; st >>= 1) {
    if (tid < st) sred[tid] += sred[tid + st];
    __syncthreads();
  }
  if (tid == 0) *loss = -sred[0] / (float)NROWS;
}

// ---------------------------------------------------------------------------
extern "C" void kernel_launch(void* const* d_in, const int* in_sizes, int n_in,
                              void* d_out, int out_size, void* d_ws, size_t ws_size,
                              hipStream_t stream)
{
  const float* x      = (const float*)d_in[0];
  const int*   t      = (const int*)  d_in[1];
  const float* W1     = (const float*)d_in[2];
  const float* b1     = (const float*)d_in[3];
  const float* W2     = (const float*)d_in[4];
  const float* b2     = (const float*)d_in[5];
  const float* W3     = (const float*)d_in[6];
  const float* b3     = (const float*)d_in[7];
  const float* head_W = (const float*)d_in[8];
  const float* head_b = (const float*)d_in[9];
  const float* t0a    = (const float*)d_in[10];
  const float* t0b    = (const float*)d_in[11];
  const float* t1a    = (const float*)d_in[12];
  const float* t1b    = (const float*)d_in[13];

  // ---- workspace layout (bf16 region, then f32 region) ----
  unsigned short* p16 = (unsigned short*)d_ws;
  unsigned short* xb  = p16; p16 += 4096ull * 512;
  unsigned short* W1b = p16; p16 += 2048ull * 512;
  unsigned short* W2b = p16; p16 += 128ull  * 2048;
  unsigned short* W3b = p16; p16 += 512ull  * 128;
  unsigned short* hWb = p16; p16 += (size_t)HEADC * 512;
  unsigned short* t0ab= p16; p16 += 128ull  * 512;
  unsigned short* t0bb= p16; p16 += 8000ull * 128;
  unsigned short* t1ab= p16; p16 += 32ull   * 512;
  unsigned short* t1bb= p16; p16 += 40000ull* 32;
  unsigned short* H1b = p16; p16 += 4096ull * 2048;
  unsigned short* H2b = p16; p16 += 4096ull * 128;
  unsigned short* Sb  = p16; p16 += 4096ull * 512;
  unsigned short* h0b = p16; p16 += 4096ull * 128;
  unsigned short* h1b = p16; p16 += 4096ull * 32;

  float* pf  = (float*)p16;
  float* pmh = pf; pf += 4096 * NH_P;
  float* psh = pf; pf += 4096 * NH_P;
  float* pm0 = pf; pf += 4096 * NC0_P;
  float* ps0 = pf; pf += 4096 * NC0_P;
  float* pm1 = pf; pf += 4096 * NC1_P;
  float* ps1 = pf; pf += 4096 * NC1_P;
  float* gsh = pf; pf += 4096;
  float* gc0 = pf; pf += 4096;
  float* gc1 = pf; pf += 4096;
  float* tg0 = pf; pf += 4096;
  float* tg1 = pf; pf += 4096;

  float* out = (float*)d_out;   // [4096] log-probs, then [1] loss

  const dim3 blk(256);

  // ---- all conversions in one launch ----
  cvt_all<<<dim3(256, 9), blk, 0, stream>>>(
      x, xb, W1, W1b, W2, W2b, W3, W3b, head_W, hWb,
      t0a, t0ab, t0b, t0bb, t1a, t1ab, t1b, t1bb);

  // ---- MLP (bf16 MFMA): 512 -> 2048 -> 128 -> 512, ReLU each ----
  gemm_mfma<2, 2, true,  true ><<<dim3(2048/64, 4096/128), blk, 0, stream>>>(xb,  W1b, b1, H1b, 4096, 2048, 512);
  gemm_mfma<2, 2, true,  true ><<<dim3(128/64,  4096/128), blk, 0, stream>>>(H1b, W2b, b2, H2b, 4096, 128,  2048);
  gemm_mfma<2, 2, true,  true ><<<dim3(512/64,  4096/128), blk, 0, stream>>>(H2b, W3b, b3, Sb,  4096, 512,  128);

  // ---- tail low-rank projections ----
  gemm_mfma<2, 2, false, false><<<dim3(128/64,  4096/128), blk, 0, stream>>>(Sb, t0ab, nullptr, h0b, 4096, 128, 512);
  gemm_mfma<4, 1, false, false><<<dim3(1,       4096/256), blk, 0, stream>>>(Sb, t1ab, nullptr, h1b, 4096, 32,  512);

  // ---- head: GEMM + fused LSE epilogue (32 col-blocks x 32 row-blocks) ----
  head_gemm_lse<<<dim3(2048/64, 4096/128), blk, 0, stream>>>(Sb, hWb, head_b, pmh, psh);

  // ---- tails: double-buffered fused LSE ----
  // tail0: 8000 = 25 y-blocks x (U=2 * NIT=10 * 16); tail1: 40000 = 125 x (5*4*16)
  fused_lse_tail<4, 2, 2, 10><<<dim3(32, NC0_P), blk, 0, stream>>>(h0b, t0bb, NC0_P, pm0, ps0);
  fused_lse_tail<1, 2, 5, 4 ><<<dim3(32, NC1_P), blk, 0, stream>>>(h1b, t1bb, NC1_P, pm1, ps1);

  // ---- gathered logits (5 dots per row) ----
  gather_kernel<<<dim3(NROWS / 4), blk, 0, stream>>>(
      Sb, hWb, head_b, h0b, t0bb, h1b, t1bb, t, gsh, gc0, gc1, tg0, tg1);

  // ---- combine + loss ----
  combine_kernel<<<dim3((NROWS + 255) / 256), blk, 0, stream>>>(
      t, pmh, psh, gsh, gc0, gc1, pm0, ps0, tg0, pm1, ps1, tg1, out);
  loss_kernel<<<dim3(1), blk, 0, stream>>>(out, out + NROWS);
}

// Round 6
// 301.077 us; speedup vs baseline: 4.6604x; 1.2947x over previous
//
#include <hip/hip_runtime.h>
#include <math.h>

typedef __attribute__((ext_vector_type(8))) short bf16x8;
typedef __attribute__((ext_vector_type(4))) float f32x4;

#define NROWS 4096
#define SHORTLIST 2000
#define HEADC 2002
#define CUT1 10000
#define C0_CLS 8000
#define C1_CLS 40000
#define L2E 1.4426950408889634f
#define LN2 0.6931471805599453f

// partial-split counts
#define NH_P  16
#define NC0_P 25
#define NC1_P 125

__device__ __forceinline__ float fexp2(float x) {
#if __has_builtin(__builtin_amdgcn_exp2f)
  return __builtin_amdgcn_exp2f(x);
#else
  return exp2f(x);
#endif
}

__device__ __forceinline__ unsigned short f2b(float f) {
  unsigned u = __float_as_uint(f);
  unsigned r = (u + 0x7FFFu + ((u >> 16) & 1u)) >> 16;
  return (unsigned short)r;
}
__device__ __forceinline__ float b2f(unsigned short u) {
  return __uint_as_float(((unsigned)u) << 16);
}

// ---------------------------------------------------------------------------
// All f32->bf16 conversions in ONE launch.
// ---------------------------------------------------------------------------
__global__ __launch_bounds__(256) void cvt_all(
    const float* __restrict__ s0, unsigned short* __restrict__ d0,  // x
    const float* __restrict__ s1, unsigned short* __restrict__ d1,  // W1
    const float* __restrict__ s2, unsigned short* __restrict__ d2,  // W2
    const float* __restrict__ s3, unsigned short* __restrict__ d3,  // W3
    const float* __restrict__ s4, unsigned short* __restrict__ d4,  // head_W
    const float* __restrict__ s5, unsigned short* __restrict__ d5,  // t0a
    const float* __restrict__ s6, unsigned short* __restrict__ d6,  // t0b
    const float* __restrict__ s7, unsigned short* __restrict__ d7,  // t1a
    const float* __restrict__ s8, unsigned short* __restrict__ d8)  // t1b
{
  const float* src; unsigned short* dst; int n4;
  switch (blockIdx.y) {
    case 0: src = s0; dst = d0; n4 = 4096 * 512 / 4;   break;
    case 1: src = s1; dst = d1; n4 = 2048 * 512 / 4;   break;
    case 2: src = s2; dst = d2; n4 = 128 * 2048 / 4;   break;
    case 3: src = s3; dst = d3; n4 = 512 * 128 / 4;    break;
    case 4: src = s4; dst = d4; n4 = HEADC * 512 / 4;  break;
    case 5: src = s5; dst = d5; n4 = 128 * 512 / 4;    break;
    case 6: src = s6; dst = d6; n4 = 8000 * 128 / 4;   break;
    case 7: src = s7; dst = d7; n4 = 32 * 512 / 4;     break;
    default: src = s8; dst = d8; n4 = 40000 * 32 / 4;  break;
  }
  for (int i = blockIdx.x * 256 + threadIdx.x; i < n4; i += 256 * gridDim.x) {
    float4 v = ((const float4*)src)[i];
    ushort4 o;
    o.x = f2b(v.x); o.y = f2b(v.y); o.z = f2b(v.z); o.w = f2b(v.w);
    ((ushort4*)dst)[i] = o;
  }
}

// ---------------------------------------------------------------------------
// LDS-staged MFMA GEMM (m97 anatomy): 128x128 tile, BK=32, 4 waves (2x2),
// reg-staged global->LDS with next-tile prefetch issued before the MFMAs.
// C = act(A[M,K] @ W[N,K]^T + bias). lda = K-total for both operands.
// SplitK via blockIdx.z: processes k in [z*Kseg, (z+1)*Kseg); F32OUT writes
// raw f32 partials to outp + z*M*N.
// ---------------------------------------------------------------------------
template<bool BIAS, bool RELU, bool F32OUT>
__global__ __launch_bounds__(256) void gemm_lds(
    const unsigned short* __restrict__ A, const unsigned short* __restrict__ W,
    const float* __restrict__ bias, void* __restrict__ outp,
    int M, int N, int lda, int Kseg)
{
  __shared__ __align__(16) unsigned short As[128 * 32];
  __shared__ __align__(16) unsigned short Bs[128 * 32];

  const int tid  = threadIdx.x;
  const int lane = tid & 63;
  const int wv   = tid >> 6;
  const int cl   = lane & 15;
  const int ko   = lane >> 4;
  const int wr   = (wv >> 1) * 64;
  const int wc   = (wv & 1) * 64;
  const int row0 = blockIdx.y * 128;
  const int col0 = blockIdx.x * 128;
  const int koff = blockIdx.z * Kseg;

  const int sr0 = tid >> 2;     // staging row (issue 0), issue 1 adds 64
  const int ssl = tid & 3;      // 16B slot within row

  f32x4 acc[4][4];
#pragma unroll
  for (int p = 0; p < 4; ++p)
#pragma unroll
    for (int q = 0; q < 4; ++q) acc[p][q] = (f32x4){0.f, 0.f, 0.f, 0.f};

  const unsigned short* aSrc = A + (size_t)(row0 + sr0) * lda + koff + ssl * 8;
  const unsigned short* bSrc = W + (size_t)(col0 + sr0) * lda + koff + ssl * 8;
  const size_t half = (size_t)64 * lda;

  bf16x8 sa0 = *(const bf16x8*)(aSrc);
  bf16x8 sa1 = *(const bf16x8*)(aSrc + half);
  bf16x8 sb0 = *(const bf16x8*)(bSrc);
  bf16x8 sb1 = *(const bf16x8*)(bSrc + half);

  const int nK = Kseg / 32;
  for (int ks = 0; ks < nK; ++ks) {
    __syncthreads();
    *(bf16x8*)&As[(size_t)sr0 * 32 + ssl * 8]        = sa0;
    *(bf16x8*)&As[(size_t)(sr0 + 64) * 32 + ssl * 8] = sa1;
    *(bf16x8*)&Bs[(size_t)sr0 * 32 + ssl * 8]        = sb0;
    *(bf16x8*)&Bs[(size_t)(sr0 + 64) * 32 + ssl * 8] = sb1;
    __syncthreads();
    if (ks + 1 < nK) {
      const int k1 = (ks + 1) * 32;
      sa0 = *(const bf16x8*)(aSrc + k1);
      sa1 = *(const bf16x8*)(aSrc + k1 + half);
      sb0 = *(const bf16x8*)(bSrc + k1);
      sb1 = *(const bf16x8*)(bSrc + k1 + half);
    }
    bf16x8 aF[4], bF[4];
#pragma unroll
    for (int p = 0; p < 4; ++p)
      aF[p] = *(const bf16x8*)&As[(size_t)(wr + p * 16 + cl) * 32 + ko * 8];
#pragma unroll
    for (int q = 0; q < 4; ++q)
      bF[q] = *(const bf16x8*)&Bs[(size_t)(wc + q * 16 + cl) * 32 + ko * 8];
#pragma unroll
    for (int p = 0; p < 4; ++p)
#pragma unroll
      for (int q = 0; q < 4; ++q)
        acc[p][q] = __builtin_amdgcn_mfma_f32_16x16x32_bf16(aF[p], bF[q], acc[p][q], 0, 0, 0);
  }

  if constexpr (F32OUT) {
    float* P = (float*)outp + (size_t)blockIdx.z * M * N;
#pragma unroll
    for (int q = 0; q < 4; ++q) {
      const int col = col0 + wc + q * 16 + cl;
#pragma unroll
      for (int p = 0; p < 4; ++p)
#pragma unroll
        for (int j = 0; j < 4; ++j) {
          const int R = row0 + wr + p * 16 + 4 * ko + j;
          P[(size_t)R * N + col] = acc[p][q][j];
        }
    }
  } else {
    unsigned short* C = (unsigned short*)outp;
#pragma unroll
    for (int q = 0; q < 4; ++q) {
      const int col = col0 + wc + q * 16 + cl;
      float bs = 0.f;
      if (BIAS) bs = bias[col];
#pragma unroll
      for (int p = 0; p < 4; ++p)
#pragma unroll
        for (int j = 0; j < 4; ++j) {
          const int R = row0 + wr + p * 16 + 4 * ko + j;
          float v = acc[p][q][j] + bs;
          if (RELU) v = fmaxf(v, 0.f);
          C[(size_t)R * N + col] = f2b(v);
        }
    }
  }
}

// ---------------------------------------------------------------------------
// Split-K reduce: out_bf16 = act(sum_z P[z] + bias). Vectorized x4. N%4==0.
// ---------------------------------------------------------------------------
template<int SK, bool BIAS, bool RELU>
__global__ __launch_bounds__(256) void splitk_reduce(
    const float* __restrict__ P, const float* __restrict__ bias,
    unsigned short* __restrict__ out, int MN4, int N)
{
  const int i = blockIdx.x * 256 + threadIdx.x;
  if (i >= MN4) return;
  float4 v = ((const float4*)P)[i];
#pragma unroll
  for (int z = 1; z < SK; ++z) {
    float4 p = ((const float4*)(P + (size_t)z * MN4 * 4))[i];
    v.x += p.x; v.y += p.y; v.z += p.z; v.w += p.w;
  }
  if (BIAS) {
    const int col = (i % (N / 4)) * 4;
    float4 b = *(const float4*)(bias + col);
    v.x += b.x; v.y += b.y; v.z += b.z; v.w += b.w;
  }
  if (RELU) {
    v.x = fmaxf(v.x, 0.f); v.y = fmaxf(v.y, 0.f);
    v.z = fmaxf(v.z, 0.f); v.w = fmaxf(v.w, 0.f);
  }
  ushort4 o;
  o.x = f2b(v.x); o.y = f2b(v.y); o.z = f2b(v.z); o.w = f2b(v.w);
  ((ushort4*)out)[i] = o;
}

// ---------------------------------------------------------------------------
// Head: LDS-staged GEMM core + fused per-row LSE epilogue over the block's
// 128 cols. Partials pm/ps [NH_P][NROWS] (log2 domain).
// ---------------------------------------------------------------------------
__global__ __launch_bounds__(256) void head_gemm_lse(
    const unsigned short* __restrict__ A,   // Sb [4096][512]
    const unsigned short* __restrict__ W,   // hWb [2002][512]
    const float* __restrict__ bias,         // head_b [2002]
    float* __restrict__ pm, float* __restrict__ ps)
{
  __shared__ __align__(16) unsigned short As[128 * 32];
  __shared__ __align__(16) unsigned short Bs[128 * 32];
  __shared__ float lm[4][64], ls[4][64];

  const int lda  = 512;
  const int tid  = threadIdx.x;
  const int lane = tid & 63;
  const int wv   = tid >> 6;
  const int cl   = lane & 15;
  const int ko   = lane >> 4;
  const int wr   = (wv >> 1) * 64;
  const int wc   = (wv & 1) * 64;
  const int row0 = blockIdx.y * 128;
  const int col0 = blockIdx.x * 128;

  const int sr0 = tid >> 2;
  const int ssl = tid & 3;

  f32x4 acc[4][4];
#pragma unroll
  for (int p = 0; p < 4; ++p)
#pragma unroll
    for (int q = 0; q < 4; ++q) acc[p][q] = (f32x4){0.f, 0.f, 0.f, 0.f};

  const unsigned short* aSrc = A + (size_t)(row0 + sr0) * lda + ssl * 8;
  const unsigned short* bSrc0 = W + (size_t)min(col0 + sr0, HEADC - 1) * lda + ssl * 8;
  const unsigned short* bSrc1 = W + (size_t)min(col0 + sr0 + 64, HEADC - 1) * lda + ssl * 8;
  const size_t half = (size_t)64 * lda;

  bf16x8 sa0 = *(const bf16x8*)(aSrc);
  bf16x8 sa1 = *(const bf16x8*)(aSrc + half);
  bf16x8 sb0 = *(const bf16x8*)(bSrc0);
  bf16x8 sb1 = *(const bf16x8*)(bSrc1);

  const int nK = 512 / 32;
  for (int ks = 0; ks < nK; ++ks) {
    __syncthreads();
    *(bf16x8*)&As[(size_t)sr0 * 32 + ssl * 8]        = sa0;
    *(bf16x8*)&As[(size_t)(sr0 + 64) * 32 + ssl * 8] = sa1;
    *(bf16x8*)&Bs[(size_t)sr0 * 32 + ssl * 8]        = sb0;
    *(bf16x8*)&Bs[(size_t)(sr0 + 64) * 32 + ssl * 8] = sb1;
    __syncthreads();
    if (ks + 1 < nK) {
      const int k1 = (ks + 1) * 32;
      sa0 = *(const bf16x8*)(aSrc + k1);
      sa1 = *(const bf16x8*)(aSrc + k1 + half);
      sb0 = *(const bf16x8*)(bSrc0 + k1);
      sb1 = *(const bf16x8*)(bSrc1 + k1);
    }
    bf16x8 aF[4], bF[4];
#pragma unroll
    for (int p = 0; p < 4; ++p)
      aF[p] = *(const bf16x8*)&As[(size_t)(wr + p * 16 + cl) * 32 + ko * 8];
#pragma unroll
    for (int q = 0; q < 4; ++q)
      bF[q] = *(const bf16x8*)&Bs[(size_t)(wc + q * 16 + cl) * 32 + ko * 8];
#pragma unroll
    for (int p = 0; p < 4; ++p)
#pragma unroll
      for (int q = 0; q < 4; ++q)
        acc[p][q] = __builtin_amdgcn_mfma_f32_16x16x32_bf16(aF[p], bF[q], acc[p][q], 0, 0, 0);
  }

  // ---- fused LSE epilogue (log2 domain) ----
  float bl2[4]; int colq[4];
#pragma unroll
  for (int q = 0; q < 4; ++q) {
    colq[q] = col0 + wc + q * 16 + cl;
    bl2[q] = bias[min(colq[q], HEADC - 1)] * L2E;
  }

  float mr[4][4], sr_[4][4];
#pragma unroll
  for (int p = 0; p < 4; ++p)
#pragma unroll
    for (int j = 0; j < 4; ++j) {
      float vv[4], mm = -3e38f;
#pragma unroll
      for (int q = 0; q < 4; ++q) {
        float v = fmaf(acc[p][q][j], L2E, bl2[q]);
        if (colq[q] >= HEADC) v = -1e30f;
        vv[q] = v;
        mm = fmaxf(mm, v);
      }
      float ss = 0.f;
#pragma unroll
      for (int q = 0; q < 4; ++q) ss += fexp2(vv[q] - mm);
      mr[p][j] = mm;
      sr_[p][j] = ss;
    }

#pragma unroll
  for (int mask = 1; mask <= 8; mask <<= 1) {
#pragma unroll
    for (int p = 0; p < 4; ++p)
#pragma unroll
      for (int j = 0; j < 4; ++j) {
        const float mo = __shfl_xor(mr[p][j], mask);
        const float so = __shfl_xor(sr_[p][j], mask);
        const float mn = fmaxf(mr[p][j], mo);
        sr_[p][j] = sr_[p][j] * fexp2(mr[p][j] - mn) + so * fexp2(mo - mn);
        mr[p][j] = mn;
      }
  }

  if (cl == 0) {
#pragma unroll
    for (int p = 0; p < 4; ++p)
#pragma unroll
      for (int j = 0; j < 4; ++j) {
        lm[wv][p * 16 + 4 * ko + j] = mr[p][j];
        ls[wv][p * 16 + 4 * ko + j] = sr_[p][j];
      }
  }
  __syncthreads();
  if (tid < 128) {
    const int pair = tid >> 6, idx = tid & 63;
    const float m0 = lm[pair * 2][idx], m1 = lm[pair * 2 + 1][idx];
    const float M = fmaxf(m0, m1);
    const float S = ls[pair * 2][idx] * fexp2(m0 - M) + ls[pair * 2 + 1][idx] * fexp2(m1 - M);
    const int grow = row0 + tid;
    pm[(size_t)blockIdx.x * NROWS + grow] = M;
    ps[(size_t)blockIdx.x * NROWS + grow] = S;
  }
}

// ---------------------------------------------------------------------------
// LDS-free MFMA GEMM (kept for the tiny N=32 projection).
// ---------------------------------------------------------------------------
template<int WR, int WC, bool BIAS, bool RELU>
__global__ __launch_bounds__(256) void gemm_mfma(
    const unsigned short* __restrict__ A, const unsigned short* __restrict__ W,
    const float* __restrict__ bias, unsigned short* __restrict__ C,
    int M, int N, int K)
{
  const int lane = threadIdx.x & 63;
  const int wv   = threadIdx.x >> 6;
  const int cl   = lane & 15;
  const int ko   = lane >> 4;
  const int rw   = (blockIdx.y * WR + (wv / WC)) * 64;
  const int cw   = (blockIdx.x * WC + (wv % WC)) * 32;

  f32x4 acc[4][2];
#pragma unroll
  for (int p = 0; p < 4; ++p)
#pragma unroll
    for (int q = 0; q < 2; ++q) acc[p][q] = (f32x4){0.f, 0.f, 0.f, 0.f};

  const unsigned short* ap = A + (size_t)(rw + cl) * K + ko * 8;
  const unsigned short* bp = W + (size_t)(cw + cl) * K + ko * 8;
  const size_t rstep = (size_t)16 * K;

#pragma unroll 2
  for (int kb = 0; kb < K; kb += 32) {
    bf16x8 a[4], b[2];
#pragma unroll
    for (int p = 0; p < 4; ++p) a[p] = *(const bf16x8*)(ap + p * rstep + kb);
#pragma unroll
    for (int q = 0; q < 2; ++q) b[q] = *(const bf16x8*)(bp + q * rstep + kb);
#pragma unroll
    for (int p = 0; p < 4; ++p)
#pragma unroll
      for (int q = 0; q < 2; ++q)
        acc[p][q] = __builtin_amdgcn_mfma_f32_16x16x32_bf16(a[p], b[q], acc[p][q], 0, 0, 0);
  }

#pragma unroll
  for (int q = 0; q < 2; ++q) {
    const int col = cw + q * 16 + cl;
    if (col >= N) continue;
    float bs = 0.f;
    if (BIAS) bs = bias[col];
#pragma unroll
    for (int p = 0; p < 4; ++p) {
#pragma unroll
      for (int j = 0; j < 4; ++j) {
        const int R = rw + p * 16 + 4 * ko + j;
        float v = acc[p][q][j] + bs;
        if (RELU) v = fmaxf(v, 0.f);
        C[(size_t)R * N + col] = f2b(v);
      }
    }
  }
}

// ---------------------------------------------------------------------------
// Tail fused GEMV + deferred-max online LSE, double-buffered W prefetch.
// ---------------------------------------------------------------------------
template<int KBLK, int ROWT, int U, int NIT>
__global__ __launch_bounds__(256) void fused_lse_tail(
    const unsigned short* __restrict__ H,   // [NROWS][K]
    const unsigned short* __restrict__ W,   // [C][K]
    int NCB,
    float* __restrict__ pm, float* __restrict__ ps)
{
  const int K    = KBLK * 32;
  const int lane = threadIdx.x & 63;
  const int wv   = threadIdx.x >> 6;
  const int cl   = lane & 15;
  const int ko   = lane >> 4;
  const int r0   = blockIdx.x * (64 * ROWT) + wv * (16 * ROWT);

  bf16x8 aF[ROWT][KBLK];
#pragma unroll
  for (int rt = 0; rt < ROWT; ++rt) {
    const unsigned short* ap = H + (size_t)(r0 + rt * 16 + cl) * K + ko * 8;
#pragma unroll
    for (int kk = 0; kk < KBLK; ++kk) aF[rt][kk] = *(const bf16x8*)(ap + kk * 32);
  }

  float m[ROWT][4], s[ROWT][4];
#pragma unroll
  for (int rt = 0; rt < ROWT; ++rt)
#pragma unroll
    for (int j = 0; j < 4; ++j) { m[rt][j] = -1e30f; s[rt][j] = 0.f; }

  const unsigned short* wbase =
      W + (size_t)(blockIdx.y * (U * NIT) * 16 + cl) * K + ko * 8;
  const size_t chunkstep = (size_t)16 * K;

  bf16x8 bA[U][KBLK], bB[U][KBLK];

  auto loadB = [&](bf16x8 (&bf)[U][KBLK], int it) {
    const unsigned short* p = wbase + (size_t)it * U * chunkstep;
#pragma unroll
    for (int u = 0; u < U; ++u)
#pragma unroll
      for (int kk = 0; kk < KBLK; ++kk)
        bf[u][kk] = *(const bf16x8*)(p + u * chunkstep + kk * 32);
  };

  auto consume = [&](bf16x8 (&bf)[U][KBLK]) {
    f32x4 acc[ROWT][U];
#pragma unroll
    for (int rt = 0; rt < ROWT; ++rt)
#pragma unroll
      for (int u = 0; u < U; ++u) acc[rt][u] = (f32x4){0.f, 0.f, 0.f, 0.f};
#pragma unroll
    for (int kk = 0; kk < KBLK; ++kk)
#pragma unroll
      for (int u = 0; u < U; ++u)
#pragma unroll
        for (int rt = 0; rt < ROWT; ++rt)
          acc[rt][u] = __builtin_amdgcn_mfma_f32_16x16x32_bf16(aF[rt][kk], bf[u][kk], acc[rt][u], 0, 0, 0);

    float nm[ROWT][4];
#pragma unroll
    for (int rt = 0; rt < ROWT; ++rt)
#pragma unroll
      for (int j = 0; j < 4; ++j) nm[rt][j] = m[rt][j];
#pragma unroll
    for (int rt = 0; rt < ROWT; ++rt)
#pragma unroll
      for (int u = 0; u < U; ++u)
#pragma unroll
        for (int j = 0; j < 4; ++j)
          nm[rt][j] = fmaxf(nm[rt][j], acc[rt][u][j] * L2E);

    float dd = -3e38f;
#pragma unroll
    for (int rt = 0; rt < ROWT; ++rt)
#pragma unroll
      for (int j = 0; j < 4; ++j) dd = fmaxf(dd, nm[rt][j] - m[rt][j]);

    if (__any(dd > 8.f)) {
#pragma unroll
      for (int rt = 0; rt < ROWT; ++rt)
#pragma unroll
        for (int j = 0; j < 4; ++j) {
          s[rt][j] *= fexp2(m[rt][j] - nm[rt][j]);
          m[rt][j] = nm[rt][j];
        }
    }
#pragma unroll
    for (int rt = 0; rt < ROWT; ++rt)
#pragma unroll
      for (int u = 0; u < U; ++u)
#pragma unroll
        for (int j = 0; j < 4; ++j)
          s[rt][j] += fexp2(fmaf(acc[rt][u][j], L2E, -m[rt][j]));
  };

  loadB(bA, 0);
#pragma unroll
  for (int it = 0; it < NIT; it += 2) {
    loadB(bB, it + 1);
    consume(bA);
    if (it + 2 < NIT) loadB(bA, it + 2);
    consume(bB);
  }

#pragma unroll
  for (int mask = 1; mask <= 8; mask <<= 1) {
#pragma unroll
    for (int rt = 0; rt < ROWT; ++rt)
#pragma unroll
      for (int j = 0; j < 4; ++j) {
        const float mo = __shfl_xor(m[rt][j], mask);
        const float so = __shfl_xor(s[rt][j], mask);
        const float mn = fmaxf(m[rt][j], mo);
        s[rt][j] = s[rt][j] * fexp2(m[rt][j] - mn) + so * fexp2(mo - mn);
        m[rt][j] = mn;
      }
  }
  if (cl == 0) {
#pragma unroll
    for (int rt = 0; rt < ROWT; ++rt)
#pragma unroll
      for (int j = 0; j < 4; ++j) {
        const int R = r0 + rt * 16 + 4 * ko + j;
        pm[(size_t)blockIdx.y * NROWS + R] = m[rt][j];
        ps[(size_t)blockIdx.y * NROWS + R] = s[rt][j];
      }
  }
}

// ---------------------------------------------------------------------------
// Target / cluster-logit gather: per row the 5 needed raw logits as dots.
// ---------------------------------------------------------------------------
__global__ __launch_bounds__(256) void gather_kernel(
    const unsigned short* __restrict__ Sb,
    const unsigned short* __restrict__ hWb,
    const float* __restrict__ head_b,
    const unsigned short* __restrict__ h0b,
    const unsigned short* __restrict__ t0bb,
    const unsigned short* __restrict__ h1b,
    const unsigned short* __restrict__ t1bb,
    const int* __restrict__ t,
    float* __restrict__ gsh, float* __restrict__ gc0, float* __restrict__ gc1,
    float* __restrict__ tg0, float* __restrict__ tg1)
{
  const int lane = threadIdx.x & 63;
  const int row  = blockIdx.x * 4 + (threadIdx.x >> 6);
  const int tv   = t[row];
  const int ch   = min(max(tv, 0), SHORTLIST - 1);
  const int c0   = min(max(tv - SHORTLIST, 0), C0_CLS - 1);
  const int c1   = min(max(tv - CUT1, 0), C1_CLS - 1);

  float acc[5] = {0.f, 0.f, 0.f, 0.f, 0.f};

  {
    bf16x8 sv = *(const bf16x8*)(Sb + (size_t)row * 512 + lane * 8);
    bf16x8 w0 = *(const bf16x8*)(hWb + (size_t)ch * 512 + lane * 8);
    bf16x8 w1 = *(const bf16x8*)(hWb + (size_t)SHORTLIST * 512 + lane * 8);
    bf16x8 w2 = *(const bf16x8*)(hWb + (size_t)(SHORTLIST + 1) * 512 + lane * 8);
#pragma unroll
    for (int e = 0; e < 8; ++e) {
      const float sf = b2f((unsigned short)sv[e]);
      acc[0] = fmaf(sf, b2f((unsigned short)w0[e]), acc[0]);
      acc[1] = fmaf(sf, b2f((unsigned short)w1[e]), acc[1]);
      acc[2] = fmaf(sf, b2f((unsigned short)w2[e]), acc[2]);
    }
  }
  if (lane < 16) {
    bf16x8 hv = *(const bf16x8*)(h0b + (size_t)row * 128 + lane * 8);
    bf16x8 wv = *(const bf16x8*)(t0bb + (size_t)c0 * 128 + lane * 8);
#pragma unroll
    for (int e = 0; e < 8; ++e)
      acc[3] = fmaf(b2f((unsigned short)hv[e]), b2f((unsigned short)wv[e]), acc[3]);
  }
  if (lane < 4) {
    bf16x8 hv = *(const bf16x8*)(h1b + (size_t)row * 32 + lane * 8);
    bf16x8 wv = *(const bf16x8*)(t1bb + (size_t)c1 * 32 + lane * 8);
#pragma unroll
    for (int e = 0; e < 8; ++e)
      acc[4] = fmaf(b2f((unsigned short)hv[e]), b2f((unsigned short)wv[e]), acc[4]);
  }

#pragma unroll
  for (int mask = 1; mask < 64; mask <<= 1)
#pragma unroll
    for (int k = 0; k < 5; ++k) acc[k] += __shfl_xor(acc[k], mask);

  if (lane == 0) {
    gsh[row] = acc[0] + head_b[ch];
    gc0[row] = acc[1] + head_b[SHORTLIST];
    gc1[row] = acc[2] + head_b[SHORTLIST + 1];
    tg0[row] = acc[3];
    tg1[row] = acc[4];
  }
}

// ---------------------------------------------------------------------------
// Combine partials (log2 domain, [NCB][NROWS] layout) into out[row]
// ---------------------------------------------------------------------------
__global__ __launch_bounds__(256) void combine_kernel(
    const int* __restrict__ t,
    const float* __restrict__ pmh, const float* __restrict__ psh,
    const float* __restrict__ gsh, const float* __restrict__ gc0,
    const float* __restrict__ gc1,
    const float* __restrict__ pm0, const float* __restrict__ ps0,
    const float* __restrict__ tg0,
    const float* __restrict__ pm1, const float* __restrict__ ps1,
    const float* __restrict__ tg1,
    float* __restrict__ out)
{
  const int r = blockIdx.x * 256 + threadIdx.x;
  if (r >= NROWS) return;

  float M = -1e30f, S = 0.f;
  for (int c = 0; c < NH_P; ++c) M = fmaxf(M, pmh[c * NROWS + r]);
  for (int c = 0; c < NH_P; ++c) S += psh[c * NROWS + r] * fexp2(pmh[c * NROWS + r] - M);
  const float hl = (M + log2f(S)) * LN2;

  const int tv = t[r];
  float o;
  if (tv < SHORTLIST) {
    o = gsh[r] - hl;
  } else if (tv < CUT1) {
    float M0 = -1e30f, S0 = 0.f;
    for (int c = 0; c < NC0_P; ++c) M0 = fmaxf(M0, pm0[c * NROWS + r]);
    for (int c = 0; c < NC0_P; ++c) S0 += ps0[c * NROWS + r] * fexp2(pm0[c * NROWS + r] - M0);
    o = (gc0[r] - hl) + (tg0[r] - (M0 + log2f(S0)) * LN2);
  } else {
    float M1 = -1e30f, S1 = 0.f;
    for (int c = 0; c < NC1_P; ++c) M1 = fmaxf(M1, pm1[c * NROWS + r]);
    for (int c = 0; c < NC1_P; ++c) S1 += ps1[c * NROWS + r] * fexp2(pm1[c * NROWS + r] - M1);
    o = (gc1[r] - hl) + (tg1[r] - (M1 + log2f(S1)) * LN2);
  }
  out[r] = o;
}

__global__ __launch_bounds__(256) void loss_kernel(
    const float* __restrict__ out, float* __restrict__ loss)
{
  __shared__ float sred[256];
  const int tid = threadIdx.x;
  float s = 0.f;
  for (int i = tid; i < NROWS; i += 256) s += out[i];
  sred[tid] = s;
  __syncthreads();
  for (int st = 128; st > 0; st >>= 1) {
    if (tid < st) sred[tid] += sred[tid + st];
    __syncthreads();
  }
  if (tid == 0) *loss = -sred[0] / (float)NROWS;
}

// ---------------------------------------------------------------------------
extern "C" void kernel_launch(void* const* d_in, const int* in_sizes, int n_in,
                              void* d_out, int out_size, void* d_ws, size_t ws_size,
                              hipStream_t stream)
{
  const float* x      = (const float*)d_in[0];
  const int*   t      = (const int*)  d_in[1];
  const float* W1     = (const float*)d_in[2];
  const float* b1     = (const float*)d_in[3];
  const float* W2     = (const float*)d_in[4];
  const float* b2     = (const float*)d_in[5];
  const float* W3     = (const float*)d_in[6];
  const float* b3     = (const float*)d_in[7];
  const float* head_W = (const float*)d_in[8];
  const float* head_b = (const float*)d_in[9];
  const float* t0a    = (const float*)d_in[10];
  const float* t0b    = (const float*)d_in[11];
  const float* t1a    = (const float*)d_in[12];
  const float* t1b    = (const float*)d_in[13];

  // ---- workspace layout (bf16 region, then f32 region) ----
  unsigned short* p16 = (unsigned short*)d_ws;
  unsigned short* xb  = p16; p16 += 4096ull * 512;
  unsigned short* W1b = p16; p16 += 2048ull * 512;
  unsigned short* W2b = p16; p16 += 128ull  * 2048;
  unsigned short* W3b = p16; p16 += 512ull  * 128;
  unsigned short* hWb = p16; p16 += (size_t)HEADC * 512;
  unsigned short* t0ab= p16; p16 += 128ull  * 512;
  unsigned short* t0bb= p16; p16 += 8000ull * 128;
  unsigned short* t1ab= p16; p16 += 32ull   * 512;
  unsigned short* t1bb= p16; p16 += 40000ull* 32;
  unsigned short* H1b = p16; p16 += 4096ull * 2048;
  unsigned short* H2b = p16; p16 += 4096ull * 128;
  unsigned short* Sb  = p16; p16 += 4096ull * 512;
  unsigned short* h0b = p16; p16 += 4096ull * 128;
  unsigned short* h1b = p16; p16 += 4096ull * 32;

  float* pf  = (float*)p16;
  float* pmh = pf; pf += 4096 * NH_P;
  float* psh = pf; pf += 4096 * NH_P;
  float* pm0 = pf; pf += 4096 * NC0_P;
  float* ps0 = pf; pf += 4096 * NC0_P;
  float* pm1 = pf; pf += 4096 * NC1_P;
  float* ps1 = pf; pf += 4096 * NC1_P;
  float* gsh = pf; pf += 4096;
  float* gc0 = pf; pf += 4096;
  float* gc1 = pf; pf += 4096;
  float* tg0 = pf; pf += 4096;
  float* tg1 = pf; pf += 4096;
  float* Pbuf = pf; pf += 4ull * 4096 * 128;   // split-K partials (reused)

  float* out = (float*)d_out;   // [4096] log-probs, then [1] loss

  const dim3 blk(256);

  // ---- all conversions in one launch ----
  cvt_all<<<dim3(256, 9), blk, 0, stream>>>(
      x, xb, W1, W1b, W2, W2b, W3, W3b, head_W, hWb,
      t0a, t0ab, t0b, t0bb, t1a, t1ab, t1b, t1bb);

  // ---- MLP (LDS-staged MFMA) ----
  gemm_lds<true, true, false><<<dim3(16, 32), blk, 0, stream>>>(
      xb, W1b, b1, H1b, 4096, 2048, 512, 512);
  gemm_lds<false, false, true><<<dim3(1, 32, 4), blk, 0, stream>>>(
      H1b, W2b, nullptr, Pbuf, 4096, 128, 2048, 512);
  splitk_reduce<4, true, true><<<dim3(512), blk, 0, stream>>>(
      Pbuf, b2, H2b, 4096 * 128 / 4, 128);
  gemm_lds<true, true, false><<<dim3(4, 32), blk, 0, stream>>>(
      H2b, W3b, b3, Sb, 4096, 512, 128, 128);

  // ---- tail low-rank projections ----
  gemm_lds<false, false, true><<<dim3(1, 32, 4), blk, 0, stream>>>(
      Sb, t0ab, nullptr, Pbuf, 4096, 128, 512, 128);
  splitk_reduce<4, false, false><<<dim3(512), blk, 0, stream>>>(
      Pbuf, nullptr, h0b, 4096 * 128 / 4, 128);
  gemm_mfma<4, 1, false, false><<<dim3(1, 16), blk, 0, stream>>>(
      Sb, t1ab, nullptr, h1b, 4096, 32, 512);

  // ---- head: LDS-staged GEMM + fused LSE epilogue ----
  head_gemm_lse<<<dim3(16, 32), blk, 0, stream>>>(Sb, hWb, head_b, pmh, psh);

  // ---- tails: double-buffered fused LSE ----
  fused_lse_tail<4, 2, 2, 10><<<dim3(32, NC0_P), blk, 0, stream>>>(h0b, t0bb, NC0_P, pm0, ps0);
  fused_lse_tail<1, 2, 5, 4 ><<<dim3(32, NC1_P), blk, 0, stream>>>(h1b, t1bb, NC1_P, pm1, ps1);

  // ---- gathered logits (5 dots per row) ----
  gather_kernel<<<dim3(NROWS / 4), blk, 0, stream>>>(
      Sb, hWb, head_b, h0b, t0bb, h1b, t1bb, t, gsh, gc0, gc1, tg0, tg1);

  // ---- combine + loss ----
  combine_kernel<<<dim3((NROWS + 255) / 256), blk, 0, stream>>>(
      t, pmh, psh, gsh, gc0, gc1, pm0, ps0, tg0, pm1, ps1, tg1, out);
  loss_kernel<<<dim3(1), blk, 0, stream>>>(out, out + NROWS);
}

// Round 7
// 294.456 us; speedup vs baseline: 4.7652x; 1.0225x over previous
//
#include <hip/hip_runtime.h>
#include <math.h>

typedef __attribute__((ext_vector_type(8))) short bf16x8;
typedef __attribute__((ext_vector_type(4))) float f32x4;

#define NROWS 4096
#define SHORTLIST 2000
#define HEADC 2002
#define CUT1 10000
#define C0_CLS 8000
#define C1_CLS 40000
#define L2E 1.4426950408889634f
#define LN2 0.6931471805599453f

// partial-split counts
#define NH_P  16
#define NC0_P 25
#define NC1_P 125

__device__ __forceinline__ float fexp2(float x) {
#if __has_builtin(__builtin_amdgcn_exp2f)
  return __builtin_amdgcn_exp2f(x);
#else
  return exp2f(x);
#endif
}

__device__ __forceinline__ unsigned short f2b(float f) {
  unsigned u = __float_as_uint(f);
  unsigned r = (u + 0x7FFFu + ((u >> 16) & 1u)) >> 16;
  return (unsigned short)r;
}
__device__ __forceinline__ float b2f(unsigned short u) {
  return __uint_as_float(((unsigned)u) << 16);
}

// bijective XCD-aware block swizzle (requires gridDim.x*gridDim.y % 8 == 0)
__device__ __forceinline__ void xcd_swz(int& bx, int& by) {
  const int gx = gridDim.x;
  const int nwg = gx * gridDim.y;
  const int orig = by * gx + bx;
  const int wg = (orig & 7) * (nwg >> 3) + (orig >> 3);
  bx = wg % gx;
  by = wg / gx;
}

// ---------------------------------------------------------------------------
// All f32->bf16 conversions in ONE launch.
// ---------------------------------------------------------------------------
__global__ __launch_bounds__(256) void cvt_all(
    const float* __restrict__ s0, unsigned short* __restrict__ d0,  // x
    const float* __restrict__ s1, unsigned short* __restrict__ d1,  // W1
    const float* __restrict__ s2, unsigned short* __restrict__ d2,  // W2
    const float* __restrict__ s3, unsigned short* __restrict__ d3,  // W3
    const float* __restrict__ s4, unsigned short* __restrict__ d4,  // head_W
    const float* __restrict__ s5, unsigned short* __restrict__ d5,  // t0a
    const float* __restrict__ s6, unsigned short* __restrict__ d6,  // t0b
    const float* __restrict__ s7, unsigned short* __restrict__ d7,  // t1a
    const float* __restrict__ s8, unsigned short* __restrict__ d8)  // t1b
{
  const float* src; unsigned short* dst; int n4;
  switch (blockIdx.y) {
    case 0: src = s0; dst = d0; n4 = 4096 * 512 / 4;   break;
    case 1: src = s1; dst = d1; n4 = 2048 * 512 / 4;   break;
    case 2: src = s2; dst = d2; n4 = 128 * 2048 / 4;   break;
    case 3: src = s3; dst = d3; n4 = 512 * 128 / 4;    break;
    case 4: src = s4; dst = d4; n4 = HEADC * 512 / 4;  break;
    case 5: src = s5; dst = d5; n4 = 128 * 512 / 4;    break;
    case 6: src = s6; dst = d6; n4 = 8000 * 128 / 4;   break;
    case 7: src = s7; dst = d7; n4 = 32 * 512 / 4;     break;
    default: src = s8; dst = d8; n4 = 40000 * 32 / 4;  break;
  }
  for (int i = blockIdx.x * 256 + threadIdx.x; i < n4; i += 256 * gridDim.x) {
    float4 v = ((const float4*)src)[i];
    ushort4 o;
    o.x = f2b(v.x); o.y = f2b(v.y); o.z = f2b(v.z); o.w = f2b(v.w);
    ((ushort4*)dst)[i] = o;
  }
}

// ---------------------------------------------------------------------------
// LDS-staged MFMA GEMM: 128x128 tile, BK=32, 4 waves (2x2), reg-staged
// global->LDS with next-tile prefetch issued before the MFMAs.
// SplitK via blockIdx.z. SCL multiplies the (post-act) output by log2(e).
// ---------------------------------------------------------------------------
template<bool BIAS, bool RELU, bool F32OUT, bool SCL>
__global__ __launch_bounds__(256) void gemm_lds(
    const unsigned short* __restrict__ A, const unsigned short* __restrict__ W,
    const float* __restrict__ bias, void* __restrict__ outp,
    int M, int N, int lda, int Kseg)
{
  __shared__ __align__(16) unsigned short As[128 * 32];
  __shared__ __align__(16) unsigned short Bs[128 * 32];

  int bx = blockIdx.x, by = blockIdx.y;
  xcd_swz(bx, by);

  const int tid  = threadIdx.x;
  const int lane = tid & 63;
  const int wv   = tid >> 6;
  const int cl   = lane & 15;
  const int ko   = lane >> 4;
  const int wr   = (wv >> 1) * 64;
  const int wc   = (wv & 1) * 64;
  const int row0 = by * 128;
  const int col0 = bx * 128;
  const int koff = blockIdx.z * Kseg;

  const int sr0 = tid >> 2;
  const int ssl = tid & 3;

  f32x4 acc[4][4];
#pragma unroll
  for (int p = 0; p < 4; ++p)
#pragma unroll
    for (int q = 0; q < 4; ++q) acc[p][q] = (f32x4){0.f, 0.f, 0.f, 0.f};

  const unsigned short* aSrc = A + (size_t)(row0 + sr0) * lda + koff + ssl * 8;
  const unsigned short* bSrc = W + (size_t)(col0 + sr0) * lda + koff + ssl * 8;
  const size_t half = (size_t)64 * lda;

  bf16x8 sa0 = *(const bf16x8*)(aSrc);
  bf16x8 sa1 = *(const bf16x8*)(aSrc + half);
  bf16x8 sb0 = *(const bf16x8*)(bSrc);
  bf16x8 sb1 = *(const bf16x8*)(bSrc + half);

  const int nK = Kseg / 32;
  for (int ks = 0; ks < nK; ++ks) {
    __syncthreads();
    *(bf16x8*)&As[(size_t)sr0 * 32 + ssl * 8]        = sa0;
    *(bf16x8*)&As[(size_t)(sr0 + 64) * 32 + ssl * 8] = sa1;
    *(bf16x8*)&Bs[(size_t)sr0 * 32 + ssl * 8]        = sb0;
    *(bf16x8*)&Bs[(size_t)(sr0 + 64) * 32 + ssl * 8] = sb1;
    __syncthreads();
    if (ks + 1 < nK) {
      const int k1 = (ks + 1) * 32;
      sa0 = *(const bf16x8*)(aSrc + k1);
      sa1 = *(const bf16x8*)(aSrc + k1 + half);
      sb0 = *(const bf16x8*)(bSrc + k1);
      sb1 = *(const bf16x8*)(bSrc + k1 + half);
    }
    bf16x8 aF[4], bF[4];
#pragma unroll
    for (int p = 0; p < 4; ++p)
      aF[p] = *(const bf16x8*)&As[(size_t)(wr + p * 16 + cl) * 32 + ko * 8];
#pragma unroll
    for (int q = 0; q < 4; ++q)
      bF[q] = *(const bf16x8*)&Bs[(size_t)(wc + q * 16 + cl) * 32 + ko * 8];
#pragma unroll
    for (int p = 0; p < 4; ++p)
#pragma unroll
      for (int q = 0; q < 4; ++q)
        acc[p][q] = __builtin_amdgcn_mfma_f32_16x16x32_bf16(aF[p], bF[q], acc[p][q], 0, 0, 0);
  }

  if constexpr (F32OUT) {
    float* P = (float*)outp + (size_t)blockIdx.z * M * N;
#pragma unroll
    for (int q = 0; q < 4; ++q) {
      const int col = col0 + wc + q * 16 + cl;
#pragma unroll
      for (int p = 0; p < 4; ++p)
#pragma unroll
        for (int j = 0; j < 4; ++j) {
          const int R = row0 + wr + p * 16 + 4 * ko + j;
          P[(size_t)R * N + col] = acc[p][q][j];
        }
    }
  } else {
    unsigned short* C = (unsigned short*)outp;
#pragma unroll
    for (int q = 0; q < 4; ++q) {
      const int col = col0 + wc + q * 16 + cl;
      float bs = 0.f;
      if (BIAS) bs = bias[col];
#pragma unroll
      for (int p = 0; p < 4; ++p)
#pragma unroll
        for (int j = 0; j < 4; ++j) {
          const int R = row0 + wr + p * 16 + 4 * ko + j;
          float v = acc[p][q][j] + bs;
          if (RELU) v = fmaxf(v, 0.f);
          if (SCL)  v *= L2E;
          C[(size_t)R * N + col] = f2b(v);
        }
    }
  }
}

// ---------------------------------------------------------------------------
// Split-K reduce: out_bf16 = act(sum_z P[z] + bias). Vectorized x4.
// ---------------------------------------------------------------------------
template<int SK, bool BIAS, bool RELU>
__global__ __launch_bounds__(256) void splitk_reduce(
    const float* __restrict__ P, const float* __restrict__ bias,
    unsigned short* __restrict__ out, int MN4, int N)
{
  const int i = blockIdx.x * 256 + threadIdx.x;
  if (i >= MN4) return;
  float4 v = ((const float4*)P)[i];
#pragma unroll
  for (int z = 1; z < SK; ++z) {
    float4 p = ((const float4*)(P + (size_t)z * MN4 * 4))[i];
    v.x += p.x; v.y += p.y; v.z += p.z; v.w += p.w;
  }
  if (BIAS) {
    const int col = (i % (N / 4)) * 4;
    float4 b = *(const float4*)(bias + col);
    v.x += b.x; v.y += b.y; v.z += b.z; v.w += b.w;
  }
  if (RELU) {
    v.x = fmaxf(v.x, 0.f); v.y = fmaxf(v.y, 0.f);
    v.z = fmaxf(v.z, 0.f); v.w = fmaxf(v.w, 0.f);
  }
  ushort4 o;
  o.x = f2b(v.x); o.y = f2b(v.y); o.z = f2b(v.z); o.w = f2b(v.w);
  ((ushort4*)out)[i] = o;
}

// ---------------------------------------------------------------------------
// Head: LDS-staged GEMM + fused per-row LSE epilogue. A (=S) is pre-scaled
// by log2(e), so acc is already in log2 domain; bias added as bias*L2E.
// Partials pm/ps [NH_P][NROWS] (log2 domain).
// ---------------------------------------------------------------------------
__global__ __launch_bounds__(256) void head_gemm_lse(
    const unsigned short* __restrict__ A,   // Sb [4096][512] (log2-scaled)
    const unsigned short* __restrict__ W,   // hWb [2002][512]
    const float* __restrict__ bias,         // head_b [2002]
    float* __restrict__ pm, float* __restrict__ ps)
{
  __shared__ __align__(16) unsigned short As[128 * 32];
  __shared__ __align__(16) unsigned short Bs[128 * 32];
  __shared__ float lm[4][64], ls[4][64];

  int bx = blockIdx.x, by = blockIdx.y;
  xcd_swz(bx, by);

  const int lda  = 512;
  const int tid  = threadIdx.x;
  const int lane = tid & 63;
  const int wv   = tid >> 6;
  const int cl   = lane & 15;
  const int ko   = lane >> 4;
  const int wr   = (wv >> 1) * 64;
  const int wc   = (wv & 1) * 64;
  const int row0 = by * 128;
  const int col0 = bx * 128;

  const int sr0 = tid >> 2;
  const int ssl = tid & 3;

  f32x4 acc[4][4];
#pragma unroll
  for (int p = 0; p < 4; ++p)
#pragma unroll
    for (int q = 0; q < 4; ++q) acc[p][q] = (f32x4){0.f, 0.f, 0.f, 0.f};

  const unsigned short* aSrc = A + (size_t)(row0 + sr0) * lda + ssl * 8;
  const unsigned short* bSrc0 = W + (size_t)min(col0 + sr0, HEADC - 1) * lda + ssl * 8;
  const unsigned short* bSrc1 = W + (size_t)min(col0 + sr0 + 64, HEADC - 1) * lda + ssl * 8;
  const size_t half = (size_t)64 * lda;

  bf16x8 sa0 = *(const bf16x8*)(aSrc);
  bf16x8 sa1 = *(const bf16x8*)(aSrc + half);
  bf16x8 sb0 = *(const bf16x8*)(bSrc0);
  bf16x8 sb1 = *(const bf16x8*)(bSrc1);

  const int nK = 512 / 32;
  for (int ks = 0; ks < nK; ++ks) {
    __syncthreads();
    *(bf16x8*)&As[(size_t)sr0 * 32 + ssl * 8]        = sa0;
    *(bf16x8*)&As[(size_t)(sr0 + 64) * 32 + ssl * 8] = sa1;
    *(bf16x8*)&Bs[(size_t)sr0 * 32 + ssl * 8]        = sb0;
    *(bf16x8*)&Bs[(size_t)(sr0 + 64) * 32 + ssl * 8] = sb1;
    __syncthreads();
    if (ks + 1 < nK) {
      const int k1 = (ks + 1) * 32;
      sa0 = *(const bf16x8*)(aSrc + k1);
      sa1 = *(const bf16x8*)(aSrc + k1 + half);
      sb0 = *(const bf16x8*)(bSrc0 + k1);
      sb1 = *(const bf16x8*)(bSrc1 + k1);
    }
    bf16x8 aF[4], bF[4];
#pragma unroll
    for (int p = 0; p < 4; ++p)
      aF[p] = *(const bf16x8*)&As[(size_t)(wr + p * 16 + cl) * 32 + ko * 8];
#pragma unroll
    for (int q = 0; q < 4; ++q)
      bF[q] = *(const bf16x8*)&Bs[(size_t)(wc + q * 16 + cl) * 32 + ko * 8];
#pragma unroll
    for (int p = 0; p < 4; ++p)
#pragma unroll
      for (int q = 0; q < 4; ++q)
        acc[p][q] = __builtin_amdgcn_mfma_f32_16x16x32_bf16(aF[p], bF[q], acc[p][q], 0, 0, 0);
  }

  // ---- fused LSE epilogue (log2 domain; acc already scaled) ----
  float bl2[4]; int colq[4];
#pragma unroll
  for (int q = 0; q < 4; ++q) {
    colq[q] = col0 + wc + q * 16 + cl;
    bl2[q] = bias[min(colq[q], HEADC - 1)] * L2E;
  }

  float mr[4][4], sr_[4][4];
#pragma unroll
  for (int p = 0; p < 4; ++p)
#pragma unroll
    for (int j = 0; j < 4; ++j) {
      float vv[4];
#pragma unroll
      for (int q = 0; q < 4; ++q) {
        float v = acc[p][q][j] + bl2[q];
        if (colq[q] >= HEADC) v = -1e30f;
        vv[q] = v;
      }
      const float mm = fmaxf(fmaxf(vv[0], vv[1]), fmaxf(vv[2], vv[3]));
      float ss = 0.f;
#pragma unroll
      for (int q = 0; q < 4; ++q) ss += fexp2(vv[q] - mm);
      mr[p][j] = mm;
      sr_[p][j] = ss;
    }

#pragma unroll
  for (int mask = 1; mask <= 8; mask <<= 1) {
#pragma unroll
    for (int p = 0; p < 4; ++p)
#pragma unroll
      for (int j = 0; j < 4; ++j) {
        const float mo = __shfl_xor(mr[p][j], mask);
        const float so = __shfl_xor(sr_[p][j], mask);
        const float mn = fmaxf(mr[p][j], mo);
        sr_[p][j] = sr_[p][j] * fexp2(mr[p][j] - mn) + so * fexp2(mo - mn);
        mr[p][j] = mn;
      }
  }

  if (cl == 0) {
#pragma unroll
    for (int p = 0; p < 4; ++p)
#pragma unroll
      for (int j = 0; j < 4; ++j) {
        lm[wv][p * 16 + 4 * ko + j] = mr[p][j];
        ls[wv][p * 16 + 4 * ko + j] = sr_[p][j];
      }
  }
  __syncthreads();
  if (tid < 128) {
    const int pair = tid >> 6, idx = tid & 63;
    const float m0 = lm[pair * 2][idx], m1 = lm[pair * 2 + 1][idx];
    const float M = fmaxf(m0, m1);
    const float S = ls[pair * 2][idx] * fexp2(m0 - M) + ls[pair * 2 + 1][idx] * fexp2(m1 - M);
    const int grow = row0 + tid;
    pm[(size_t)bx * NROWS + grow] = M;
    ps[(size_t)bx * NROWS + grow] = S;
  }
}

// ---------------------------------------------------------------------------
// LDS-free MFMA GEMM (kept for the tiny N=32 projection).
// ---------------------------------------------------------------------------
template<int WR, int WC, bool BIAS, bool RELU>
__global__ __launch_bounds__(256) void gemm_mfma(
    const unsigned short* __restrict__ A, const unsigned short* __restrict__ W,
    const float* __restrict__ bias, unsigned short* __restrict__ C,
    int M, int N, int K)
{
  const int lane = threadIdx.x & 63;
  const int wv   = threadIdx.x >> 6;
  const int cl   = lane & 15;
  const int ko   = lane >> 4;
  const int rw   = (blockIdx.y * WR + (wv / WC)) * 64;
  const int cw   = (blockIdx.x * WC + (wv % WC)) * 32;

  f32x4 acc[4][2];
#pragma unroll
  for (int p = 0; p < 4; ++p)
#pragma unroll
    for (int q = 0; q < 2; ++q) acc[p][q] = (f32x4){0.f, 0.f, 0.f, 0.f};

  const unsigned short* ap = A + (size_t)(rw + cl) * K + ko * 8;
  const unsigned short* bp = W + (size_t)(cw + cl) * K + ko * 8;
  const size_t rstep = (size_t)16 * K;

#pragma unroll 2
  for (int kb = 0; kb < K; kb += 32) {
    bf16x8 a[4], b[2];
#pragma unroll
    for (int p = 0; p < 4; ++p) a[p] = *(const bf16x8*)(ap + p * rstep + kb);
#pragma unroll
    for (int q = 0; q < 2; ++q) b[q] = *(const bf16x8*)(bp + q * rstep + kb);
#pragma unroll
    for (int p = 0; p < 4; ++p)
#pragma unroll
      for (int q = 0; q < 2; ++q)
        acc[p][q] = __builtin_amdgcn_mfma_f32_16x16x32_bf16(a[p], b[q], acc[p][q], 0, 0, 0);
  }

#pragma unroll
  for (int q = 0; q < 2; ++q) {
    const int col = cw + q * 16 + cl;
    if (col >= N) continue;
    float bs = 0.f;
    if (BIAS) bs = bias[col];
#pragma unroll
    for (int p = 0; p < 4; ++p) {
#pragma unroll
      for (int j = 0; j < 4; ++j) {
        const int R = rw + p * 16 + 4 * ko + j;
        float v = acc[p][q][j] + bs;
        if (RELU) v = fmaxf(v, 0.f);
        C[(size_t)R * N + col] = f2b(v);
      }
    }
  }
}

// ---------------------------------------------------------------------------
// Tail fused GEMV + deferred-max online LSE, double-buffered W prefetch.
// Inputs H are pre-scaled by log2(e) -> acc is directly in log2 domain.
// Common path per logit: fmax-tree (amortized) + sub + exp2 + add.
// ---------------------------------------------------------------------------
template<int KBLK, int ROWT, int U, int NIT>
__global__ __launch_bounds__(256) void fused_lse_tail(
    const unsigned short* __restrict__ H,   // [NROWS][K] (log2-scaled)
    const unsigned short* __restrict__ W,   // [C][K]
    int NCB,
    float* __restrict__ pm, float* __restrict__ ps)
{
  const int K    = KBLK * 32;
  const int lane = threadIdx.x & 63;
  const int wv   = threadIdx.x >> 6;
  const int cl   = lane & 15;
  const int ko   = lane >> 4;
  const int r0   = blockIdx.x * (64 * ROWT) + wv * (16 * ROWT);

  bf16x8 aF[ROWT][KBLK];
#pragma unroll
  for (int rt = 0; rt < ROWT; ++rt) {
    const unsigned short* ap = H + (size_t)(r0 + rt * 16 + cl) * K + ko * 8;
#pragma unroll
    for (int kk = 0; kk < KBLK; ++kk) aF[rt][kk] = *(const bf16x8*)(ap + kk * 32);
  }

  float m[ROWT][4], s[ROWT][4], s2[ROWT][4];
#pragma unroll
  for (int rt = 0; rt < ROWT; ++rt)
#pragma unroll
    for (int j = 0; j < 4; ++j) { m[rt][j] = -1e30f; s[rt][j] = 0.f; s2[rt][j] = 0.f; }

  const unsigned short* wbase =
      W + (size_t)(blockIdx.y * (U * NIT) * 16 + cl) * K + ko * 8;
  const size_t chunkstep = (size_t)16 * K;

  bf16x8 bA[U][KBLK], bB[U][KBLK];

  auto loadB = [&](bf16x8 (&bf)[U][KBLK], int it) {
    const unsigned short* p = wbase + (size_t)it * U * chunkstep;
#pragma unroll
    for (int u = 0; u < U; ++u)
#pragma unroll
      for (int kk = 0; kk < KBLK; ++kk)
        bf[u][kk] = *(const bf16x8*)(p + u * chunkstep + kk * 32);
  };

  auto consume = [&](bf16x8 (&bf)[U][KBLK]) {
    f32x4 acc[ROWT][U];
#pragma unroll
    for (int rt = 0; rt < ROWT; ++rt)
#pragma unroll
      for (int u = 0; u < U; ++u) acc[rt][u] = (f32x4){0.f, 0.f, 0.f, 0.f};
#pragma unroll
    for (int kk = 0; kk < KBLK; ++kk)
#pragma unroll
      for (int u = 0; u < U; ++u)
#pragma unroll
        for (int rt = 0; rt < ROWT; ++rt)
          acc[rt][u] = __builtin_amdgcn_mfma_f32_16x16x32_bf16(aF[rt][kk], bf[u][kk], acc[rt][u], 0, 0, 0);

    // per-(rt,j) chunk max via fmax tree (no scaling: already log2 domain)
    float cm[ROWT][4];
#pragma unroll
    for (int rt = 0; rt < ROWT; ++rt)
#pragma unroll
      for (int j = 0; j < 4; ++j) {
        float c = acc[rt][0][j];
#pragma unroll
        for (int u = 1; u < U; ++u) c = fmaxf(c, acc[rt][u][j]);
        cm[rt][j] = c;
      }

    float dd = -3e38f;
#pragma unroll
    for (int rt = 0; rt < ROWT; ++rt)
#pragma unroll
      for (int j = 0; j < 4; ++j) dd = fmaxf(dd, cm[rt][j] - m[rt][j]);

    if (__any(dd > 8.f)) {
#pragma unroll
      for (int rt = 0; rt < ROWT; ++rt)
#pragma unroll
        for (int j = 0; j < 4; ++j) {
          const float mn = fmaxf(m[rt][j], cm[rt][j]);
          const float sc = fexp2(m[rt][j] - mn);
          s[rt][j] *= sc; s2[rt][j] *= sc;
          m[rt][j] = mn;
        }
    }
#pragma unroll
    for (int rt = 0; rt < ROWT; ++rt)
#pragma unroll
      for (int u = 0; u < U; ++u)
#pragma unroll
        for (int j = 0; j < 4; ++j) {
          const float e = fexp2(acc[rt][u][j] - m[rt][j]);
          if (u & 1) s2[rt][j] += e; else s[rt][j] += e;
        }
  };

  loadB(bA, 0);
#pragma unroll
  for (int it = 0; it < NIT; it += 2) {
    loadB(bB, it + 1);
    consume(bA);
    if (it + 2 < NIT) loadB(bA, it + 2);
    consume(bB);
  }

#pragma unroll
  for (int rt = 0; rt < ROWT; ++rt)
#pragma unroll
    for (int j = 0; j < 4; ++j) s[rt][j] += s2[rt][j];

#pragma unroll
  for (int mask = 1; mask <= 8; mask <<= 1) {
#pragma unroll
    for (int rt = 0; rt < ROWT; ++rt)
#pragma unroll
      for (int j = 0; j < 4; ++j) {
        const float mo = __shfl_xor(m[rt][j], mask);
        const float so = __shfl_xor(s[rt][j], mask);
        const float mn = fmaxf(m[rt][j], mo);
        s[rt][j] = s[rt][j] * fexp2(m[rt][j] - mn) + so * fexp2(mo - mn);
        m[rt][j] = mn;
      }
  }
  if (cl == 0) {
#pragma unroll
    for (int rt = 0; rt < ROWT; ++rt)
#pragma unroll
      for (int j = 0; j < 4; ++j) {
        const int R = r0 + rt * 16 + 4 * ko + j;
        pm[(size_t)blockIdx.y * NROWS + R] = m[rt][j];
        ps[(size_t)blockIdx.y * NROWS + R] = s[rt][j];
      }
  }
}

// ---------------------------------------------------------------------------
// Target / cluster-logit gather (log2 domain: inputs pre-scaled, bias * L2E).
// ---------------------------------------------------------------------------
__global__ __launch_bounds__(256) void gather_kernel(
    const unsigned short* __restrict__ Sb,
    const unsigned short* __restrict__ hWb,
    const float* __restrict__ head_b,
    const unsigned short* __restrict__ h0b,
    const unsigned short* __restrict__ t0bb,
    const unsigned short* __restrict__ h1b,
    const unsigned short* __restrict__ t1bb,
    const int* __restrict__ t,
    float* __restrict__ gsh, float* __restrict__ gc0, float* __restrict__ gc1,
    float* __restrict__ tg0, float* __restrict__ tg1)
{
  const int lane = threadIdx.x & 63;
  const int row  = blockIdx.x * 4 + (threadIdx.x >> 6);
  const int tv   = t[row];
  const int ch   = min(max(tv, 0), SHORTLIST - 1);
  const int c0   = min(max(tv - SHORTLIST, 0), C0_CLS - 1);
  const int c1   = min(max(tv - CUT1, 0), C1_CLS - 1);

  float acc[5] = {0.f, 0.f, 0.f, 0.f, 0.f};

  {
    bf16x8 sv = *(const bf16x8*)(Sb + (size_t)row * 512 + lane * 8);
    bf16x8 w0 = *(const bf16x8*)(hWb + (size_t)ch * 512 + lane * 8);
    bf16x8 w1 = *(const bf16x8*)(hWb + (size_t)SHORTLIST * 512 + lane * 8);
    bf16x8 w2 = *(const bf16x8*)(hWb + (size_t)(SHORTLIST + 1) * 512 + lane * 8);
#pragma unroll
    for (int e = 0; e < 8; ++e) {
      const float sf = b2f((unsigned short)sv[e]);
      acc[0] = fmaf(sf, b2f((unsigned short)w0[e]), acc[0]);
      acc[1] = fmaf(sf, b2f((unsigned short)w1[e]), acc[1]);
      acc[2] = fmaf(sf, b2f((unsigned short)w2[e]), acc[2]);
    }
  }
  if (lane < 16) {
    bf16x8 hv = *(const bf16x8*)(h0b + (size_t)row * 128 + lane * 8);
    bf16x8 wv = *(const bf16x8*)(t0bb + (size_t)c0 * 128 + lane * 8);
#pragma unroll
    for (int e = 0; e < 8; ++e)
      acc[3] = fmaf(b2f((unsigned short)hv[e]), b2f((unsigned short)wv[e]), acc[3]);
  }
  if (lane < 4) {
    bf16x8 hv = *(const bf16x8*)(h1b + (size_t)row * 32 + lane * 8);
    bf16x8 wv = *(const bf16x8*)(t1bb + (size_t)c1 * 32 + lane * 8);
#pragma unroll
    for (int e = 0; e < 8; ++e)
      acc[4] = fmaf(b2f((unsigned short)hv[e]), b2f((unsigned short)wv[e]), acc[4]);
  }

#pragma unroll
  for (int mask = 1; mask < 64; mask <<= 1)
#pragma unroll
    for (int k = 0; k < 5; ++k) acc[k] += __shfl_xor(acc[k], mask);

  if (lane == 0) {
    gsh[row] = acc[0] + head_b[ch] * L2E;
    gc0[row] = acc[1] + head_b[SHORTLIST] * L2E;
    gc1[row] = acc[2] + head_b[SHORTLIST + 1] * L2E;
    tg0[row] = acc[3];
    tg1[row] = acc[4];
  }
}

// ---------------------------------------------------------------------------
// Combine partials (all log2 domain); single *LN2 at the end.
// ---------------------------------------------------------------------------
__global__ __launch_bounds__(256) void combine_kernel(
    const int* __restrict__ t,
    const float* __restrict__ pmh, const float* __restrict__ psh,
    const float* __restrict__ gsh, const float* __restrict__ gc0,
    const float* __restrict__ gc1,
    const float* __restrict__ pm0, const float* __restrict__ ps0,
    const float* __restrict__ tg0,
    const float* __restrict__ pm1, const float* __restrict__ ps1,
    const float* __restrict__ tg1,
    float* __restrict__ out)
{
  const int r = blockIdx.x * 256 + threadIdx.x;
  if (r >= NROWS) return;

  float M = -1e30f, S = 0.f;
  for (int c = 0; c < NH_P; ++c) M = fmaxf(M, pmh[c * NROWS + r]);
  for (int c = 0; c < NH_P; ++c) S += psh[c * NROWS + r] * fexp2(pmh[c * NROWS + r] - M);
  const float hl2 = M + log2f(S);

  const int tv = t[r];
  float o2;
  if (tv < SHORTLIST) {
    o2 = gsh[r] - hl2;
  } else if (tv < CUT1) {
    float M0 = -1e30f, S0 = 0.f;
    for (int c = 0; c < NC0_P; ++c) M0 = fmaxf(M0, pm0[c * NROWS + r]);
    for (int c = 0; c < NC0_P; ++c) S0 += ps0[c * NROWS + r] * fexp2(pm0[c * NROWS + r] - M0);
    o2 = (gc0[r] - hl2) + (tg0[r] - (M0 + log2f(S0)));
  } else {
    float M1 = -1e30f, S1 = 0.f;
    for (int c = 0; c < NC1_P; ++c) M1 = fmaxf(M1, pm1[c * NROWS + r]);
    for (int c = 0; c < NC1_P; ++c) S1 += ps1[c * NROWS + r] * fexp2(pm1[c * NROWS + r] - M1);
    o2 = (gc1[r] - hl2) + (tg1[r] - (M1 + log2f(S1)));
  }
  out[r] = o2 * LN2;
}

__global__ __launch_bounds__(256) void loss_kernel(
    const float* __restrict__ out, float* __restrict__ loss)
{
  __shared__ float sred[256];
  const int tid = threadIdx.x;
  float s = 0.f;
  for (int i = tid; i < NROWS; i += 256) s += out[i];
  sred[tid] = s;
  __syncthreads();
  for (int st = 128; st > 0; st >>= 1) {
    if (tid < st) sred[tid] += sred[tid + st];
    __syncthreads();
  }
  if (tid == 0) *loss = -sred[0] / (float)NROWS;
}

// ---------------------------------------------------------------------------
extern "C" void kernel_launch(void* const* d_in, const int* in_sizes, int n_in,
                              void* d_out, int out_size, void* d_ws, size_t ws_size,
                              hipStream_t stream)
{
  const float* x      = (const float*)d_in[0];
  const int*   t      = (const int*)  d_in[1];
  const float* W1     = (const float*)d_in[2];
  const float* b1     = (const float*)d_in[3];
  const float* W2     = (const float*)d_in[4];
  const float* b2     = (const float*)d_in[5];
  const float* W3     = (const float*)d_in[6];
  const float* b3     = (const float*)d_in[7];
  const float* head_W = (const float*)d_in[8];
  const float* head_b = (const float*)d_in[9];
  const float* t0a    = (const float*)d_in[10];
  const float* t0b    = (const float*)d_in[11];
  const float* t1a    = (const float*)d_in[12];
  const float* t1b    = (const float*)d_in[13];

  // ---- workspace layout (bf16 region, then f32 region) ----
  unsigned short* p16 = (unsigned short*)d_ws;
  unsigned short* xb  = p16; p16 += 4096ull * 512;
  unsigned short* W1b = p16; p16 += 2048ull * 512;
  unsigned short* W2b = p16; p16 += 128ull  * 2048;
  unsigned short* W3b = p16; p16 += 512ull  * 128;
  unsigned short* hWb = p16; p16 += (size_t)HEADC * 512;
  unsigned short* t0ab= p16; p16 += 128ull  * 512;
  unsigned short* t0bb= p16; p16 += 8000ull * 128;
  unsigned short* t1ab= p16; p16 += 32ull   * 512;
  unsigned short* t1bb= p16; p16 += 40000ull* 32;
  unsigned short* H1b = p16; p16 += 4096ull * 2048;
  unsigned short* H2b = p16; p16 += 4096ull * 128;
  unsigned short* Sb  = p16; p16 += 4096ull * 512;   // log2-scaled S
  unsigned short* h0b = p16; p16 += 4096ull * 128;   // log2-scaled h0
  unsigned short* h1b = p16; p16 += 4096ull * 32;    // log2-scaled h1

  float* pf  = (float*)p16;
  float* pmh = pf; pf += 4096 * NH_P;
  float* psh = pf; pf += 4096 * NH_P;
  float* pm0 = pf; pf += 4096 * NC0_P;
  float* ps0 = pf; pf += 4096 * NC0_P;
  float* pm1 = pf; pf += 4096 * NC1_P;
  float* ps1 = pf; pf += 4096 * NC1_P;
  float* gsh = pf; pf += 4096;
  float* gc0 = pf; pf += 4096;
  float* gc1 = pf; pf += 4096;
  float* tg0 = pf; pf += 4096;
  float* tg1 = pf; pf += 4096;
  float* Pbuf = pf; pf += 4ull * 4096 * 128;   // split-K partials (reused)

  float* out = (float*)d_out;   // [4096] log-probs, then [1] loss

  const dim3 blk(256);

  // ---- all conversions in one launch ----
  cvt_all<<<dim3(256, 9), blk, 0, stream>>>(
      x, xb, W1, W1b, W2, W2b, W3, W3b, head_W, hWb,
      t0a, t0ab, t0b, t0bb, t1a, t1ab, t1b, t1bb);

  // ---- MLP (LDS-staged MFMA); GEMM3 output scaled by log2(e) ----
  gemm_lds<true, true, false, false><<<dim3(16, 32), blk, 0, stream>>>(
      xb, W1b, b1, H1b, 4096, 2048, 512, 512);
  gemm_lds<false, false, true, false><<<dim3(1, 32, 4), blk, 0, stream>>>(
      H1b, W2b, nullptr, Pbuf, 4096, 128, 2048, 512);
  splitk_reduce<4, true, true><<<dim3(512), blk, 0, stream>>>(
      Pbuf, b2, H2b, 4096 * 128 / 4, 128);
  gemm_lds<true, true, false, true><<<dim3(4, 32), blk, 0, stream>>>(
      H2b, W3b, b3, Sb, 4096, 512, 128, 128);

  // ---- tail low-rank projections (inherit log2 scaling from Sb) ----
  gemm_lds<false, false, true, false><<<dim3(1, 32, 4), blk, 0, stream>>>(
      Sb, t0ab, nullptr, Pbuf, 4096, 128, 512, 128);
  splitk_reduce<4, false, false><<<dim3(512), blk, 0, stream>>>(
      Pbuf, nullptr, h0b, 4096 * 128 / 4, 128);
  gemm_mfma<4, 1, false, false><<<dim3(1, 16), blk, 0, stream>>>(
      Sb, t1ab, nullptr, h1b, 4096, 32, 512);

  // ---- head: LDS-staged GEMM + fused LSE epilogue ----
  head_gemm_lse<<<dim3(16, 32), blk, 0, stream>>>(Sb, hWb, head_b, pmh, psh);

  // ---- tails: double-buffered fused LSE ----
  fused_lse_tail<4, 2, 2, 10><<<dim3(32, NC0_P), blk, 0, stream>>>(h0b, t0bb, NC0_P, pm0, ps0);
  fused_lse_tail<1, 2, 5, 4 ><<<dim3(32, NC1_P), blk, 0, stream>>>(h1b, t1bb, NC1_P, pm1, ps1);

  // ---- gathered logits (5 dots per row) ----
  gather_kernel<<<dim3(NROWS / 4), blk, 0, stream>>>(
      Sb, hWb, head_b, h0b, t0bb, h1b, t1bb, t, gsh, gc0, gc1, tg0, tg1);

  // ---- combine + loss ----
  combine_kernel<<<dim3((NROWS + 255) / 256), blk, 0, stream>>>(
      t, pmh, psh, gsh, gc0, gc1, pm0, ps0, tg0, pm1, ps1, tg1, out);
  loss_kernel<<<dim3(1), blk, 0, stream>>>(out, out + NROWS);
}